// Round 13
// baseline (1112.910 us; speedup 1.0000x reference)
//
#include <hip/hip_runtime.h>
#include <hip/hip_bf16.h>
#include <cstdint>
#include <cstddef>

#define Sd 1024
#define Dd 512
#define Hd 8
#define Fd 2048
#define Bd 8
#define EPSf 1e-3f

typedef __bf16 bf16x8 __attribute__((ext_vector_type(8)));
typedef float f32x4 __attribute__((ext_vector_type(4)));
typedef __attribute__((address_space(3))) unsigned int lds_u32;
typedef __attribute__((address_space(1))) const unsigned int gl_u32;

#define BM 128
#define BN 128
#define BK 32

enum { EPI_BF16 = 0, EPI_F32 = 1, EPI_BNPRELU = 2 };

__device__ __forceinline__ void gl_lds16(const void* g, void* l) {
  __builtin_amdgcn_global_load_lds((gl_u32*)g, (lds_u32*)l, 16, 0, 0);
}
__device__ inline unsigned short f2b_(float f) {
  __hip_bfloat16 h = __float2bfloat16(f); unsigned short s; __builtin_memcpy(&s, &h, 2); return s;
}

// ======================================================================
// Fused attention middle (flash-style, no-max exp — validated R8):
// per WG: slice z=(b,h), M-tile 32 rows. A = P rows resident in LDS
// (swizzled, staged once; in-place R write-back is WG-exclusive).
// Loop 8 KV-tiles of 128: S=A@K^T (K direct global->VGPR, 16 ksteps),
// epi: e=exp((S+u+w+c)/D) -> LDS S_exp (swz) + local rsum; PV: O += S_exp@V
// (V direct global). End: R = O / rsum. grid (32, 64), 512 thr.
// LDS 40.1KiB -> 3 WG/CU. z-slice XCD affinity via id&7.
// ======================================================================
__global__ __launch_bounds__(512, 4) void attn_fused(
    __hip_bfloat16* __restrict__ P,          // PR [8192][4096] (in/out)
    const __hip_bfloat16* __restrict__ Kb,   // kbf [8192][512]
    const __hip_bfloat16* __restrict__ Vt,   // vbft [8][512][1024]
    const float* __restrict__ u, const float* __restrict__ w,
    const float* __restrict__ cv) {
  __shared__ __align__(16) char ldsA[32768];  // [32][512] bf16 swz
  __shared__ __align__(16) char ldsS[8192];   // [32][128] bf16 swz
  __shared__ float rsum[32];
  const int tid = threadIdx.x;
  const int id = blockIdx.x + 32 * blockIdx.y;
  const int xcd = id & 7, slot = id >> 3;
  const int z = xcd + 8 * (slot >> 5);   // slice in [0,64)
  const int m0 = (slot & 31) * 32;
  const int b = z >> 3, h = z & 7;

  const int lane = tid & 63, wid = tid >> 6;
  const int fr = lane & 15, kg = lane >> 4;
  const int mS = wid >> 2, nS = wid & 3;   // S-phase: 2m x 4n waves

  // ---- stage A (pre-swizzled source; linear gl_lds dest) ----
#pragma unroll
  for (int p = 0; p < 4; ++p) {
    const int s = p * 512 + tid;
    const int r = s >> 6, c = s & 63;
    const int sc_ = (c & ~7) | ((c & 7) ^ (r & 7));
    gl_lds16((const char*)P + ((size_t)(b * 1024 + m0 + r)) * 8192 + h * 1024 + sc_ * 16,
             ldsA + s * 16);
  }
  if (tid < 32) rsum[tid] = 0.f;
  __syncthreads();

  const float cvh = cv[h];
  const float* us = u + h * 8192 + b * 1024 + m0;
  const float* wsb = w + h * 8192 + b * 1024;
  const char* Kbase = (const char*)Kb + (size_t)b * 1048576;
  const char* Vbase = (const char*)Vt + (size_t)b * 1048576;
  const char* aRow = ldsA + (mS * 16 + fr) * 1024;
  const float alpha = 1.f / (float)Dd;

  f32x4 O[2][4] = {};

  for (int t = 0; t < 8; ++t) {
    const int t0 = t * 128;
    // ---- S-phase: Sacc = A @ K_t^T ----
    f32x4 Sacc[2] = {};
    const char* kRow = Kbase + (size_t)(t0 + nS * 32 + fr) * 1024 + kg * 16;
    bf16x8 kf0 = *(const bf16x8*)(kRow);
    bf16x8 kf1 = *(const bf16x8*)(kRow + 16384);
#pragma unroll
    for (int ks = 0; ks < 16; ++ks) {
      bf16x8 kn0, kn1;
      if (ks + 1 < 16) {
        kn0 = *(const bf16x8*)(kRow + (ks + 1) * 64);
        kn1 = *(const bf16x8*)(kRow + 16384 + (ks + 1) * 64);
      }
      const int c = ks * 4 + kg;
      const int sc_ = (c & ~7) | ((c & 7) ^ (fr & 7));
      const bf16x8 af = *(const bf16x8*)(aRow + sc_ * 16);
      Sacc[0] = __builtin_amdgcn_mfma_f32_16x16x32_bf16(af, kf0, Sacc[0], 0, 0, 0);
      Sacc[1] = __builtin_amdgcn_mfma_f32_16x16x32_bf16(af, kf1, Sacc[1], 0, 0, 0);
      kf0 = kn0; kf1 = kn1;
    }
    // ---- epi: exp, rsum, S_exp -> LDS ----
    float part[4] = {0.f, 0.f, 0.f, 0.f};
#pragma unroll
    for (int ni = 0; ni < 2; ++ni) {
      const int tl = nS * 32 + ni * 16 + fr;
      const float wv_ = wsb[t0 + tl];
      const int chb = tl >> 3;
#pragma unroll
      for (int j = 0; j < 4; ++j) {
        const int rl = mS * 16 + kg * 4 + j;
        const float e = __expf((Sacc[ni][j] + us[rl] + wv_ + cvh) * alpha);
        part[j] += e;
        const int ch = (chb & ~7) | ((chb & 7) ^ (rl & 7));
        *(unsigned short*)(ldsS + rl * 256 + ch * 16 + (tl & 7) * 2) = f2b_(e);
      }
    }
#pragma unroll
    for (int j = 0; j < 4; ++j) {
      float v = part[j];
      v += __shfl_xor(v, 1); v += __shfl_xor(v, 2);
      v += __shfl_xor(v, 4); v += __shfl_xor(v, 8);
      if (fr == 0) atomicAdd(&rsum[mS * 16 + kg * 4 + j], v);
    }
    __syncthreads();
    // ---- PV-phase: O += S_exp @ V_t (wave = d-block wid*64) ----
#pragma unroll
    for (int ks = 0; ks < 4; ++ks) {
      bf16x8 vf[4];
#pragma unroll
      for (int ni = 0; ni < 4; ++ni)
        vf[ni] = *(const bf16x8*)(Vbase + (size_t)(wid * 64 + ni * 16 + fr) * 2048 +
                                  (size_t)t0 * 2 + ks * 64 + kg * 16);
      bf16x8 sa[2];
#pragma unroll
      for (int mi = 0; mi < 2; ++mi) {
        const int c = ks * 4 + kg;
        const int ch = (c & ~7) | ((c & 7) ^ (fr & 7));
        sa[mi] = *(const bf16x8*)(ldsS + (mi * 16 + fr) * 256 + ch * 16);
      }
#pragma unroll
      for (int mi = 0; mi < 2; ++mi)
#pragma unroll
        for (int ni = 0; ni < 4; ++ni)
          O[mi][ni] = __builtin_amdgcn_mfma_f32_16x16x32_bf16(sa[mi], vf[ni], O[mi][ni], 0, 0, 0);
    }
    __syncthreads();
  }

  // ---- normalize + in-place write R ----
  float rinv[2][4];
#pragma unroll
  for (int mi = 0; mi < 2; ++mi)
#pragma unroll
    for (int j = 0; j < 4; ++j)
      rinv[mi][j] = 1.f / rsum[mi * 16 + kg * 4 + j];
#pragma unroll
  for (int mi = 0; mi < 2; ++mi)
#pragma unroll
    for (int ni = 0; ni < 4; ++ni) {
      const int col = h * 512 + wid * 64 + ni * 16 + fr;
#pragma unroll
      for (int j = 0; j < 4; ++j) {
        const size_t row = (size_t)b * 1024 + m0 + mi * 16 + kg * 4 + j;
        P[row * 4096 + col] = __float2bfloat16(O[mi][ni][j] * rinv[mi][j]);
      }
    }
}

// ======================================================================
// 256x256 GEMM (frozen R6 core): counted-lgkmcnt pipeline.
// ======================================================================
#define LGKM(n)                                                  \
  asm volatile("s_waitcnt lgkmcnt(" #n ")" ::: "memory");        \
  __builtin_amdgcn_sched_barrier(0)
#define VMC(n) asm volatile("s_waitcnt vmcnt(" #n ")" ::: "memory")

#define LDA_(dst, dof, xr, mh)                                               \
  _Pragma("unroll") for (int i_ = 0; i_ < 4; ++i_)                           \
      dst[i_] = *(const bf16x8*)(aw + (dof) + (xr) + (mh) * 8192 + i_ * 2048);
#define LDB_(dst, dof, xr)                                                   \
  _Pragma("unroll") for (int i_ = 0; i_ < 4; ++i_)                           \
      dst[i_] = *(const bf16x8*)(bw + (dof) + (xr) + i_ * 2048);
#define MFMAQ(q, av, bv)                                                     \
  __builtin_amdgcn_s_setprio(1);                                             \
  {                                                                          \
    _Pragma("unroll") for (int i_ = 0; i_ < 4; ++i_) {                       \
      _Pragma("unroll") for (int n_ = 0; n_ < 4; ++n_)                       \
          acc[(q) * 4 + i_][n_] = __builtin_amdgcn_mfma_f32_16x16x32_bf16(   \
              av[i_], bv[n_], acc[(q) * 4 + i_][n_], 0, 0, 0);               \
    }                                                                        \
  }                                                                          \
  __builtin_amdgcn_s_setprio(0)

template <int EPI>
__global__ __launch_bounds__(512, 2) void big_gemm(
    const __hip_bfloat16* __restrict__ A_, int lda, size_t sA1, size_t sA2,
    const __hip_bfloat16* __restrict__ B_, size_t sB1,
    const float* __restrict__ bias_,
    void* __restrict__ C_, int ldc, size_t sC, int K, float alpha,
    const float* __restrict__ bn_g, const float* __restrict__ bn_b,
    const float* __restrict__ bn_m, const float* __restrict__ bn_v,
    const float* __restrict__ pa) {
  __shared__ __align__(16) char lds[131072];
  const int tid = threadIdx.x;
  const int gx = gridDim.x;
  const int nwg = gx * gridDim.y;
  const int orig = blockIdx.y * gx + blockIdx.x;
  const int wgid = (orig & 7) * (nwg >> 3) + (orig >> 3);
  const int bx = wgid % gx;
  const int by = wgid / gx;
  const int m0 = by * 256, n0 = bx * 256;
  const int z = blockIdx.z;
  const int z1 = z >> 3, z2 = z & 7;

  const int lane = tid & 63;
  const int wid = tid >> 6;
  const int wm = wid >> 2;
  const int wn = wid & 3;
  const int fr = lane & 15;
  const int kg = lane >> 4;

  const int r0 = tid >> 3;
  const int c0 = (tid & 7) ^ (r0 & 7);
  const size_t lda2 = (size_t)lda * 2;
  const size_t ldb2 = (size_t)K * 2;
  const char* Ab = (const char*)(A_ + (size_t)z1 * sA1 + (size_t)z2 * sA2) +
                   (size_t)(m0 + r0) * lda2 + c0 * 16;
  const char* Bb = (const char*)(B_ + (size_t)z1 * sB1) + (size_t)(n0 + r0) * ldb2 + c0 * 16;

  const int axor0 = (kg ^ (fr & 7)) << 4;
  const int axor1 = ((4 + kg) ^ (fr & 7)) << 4;
  const char* aw = lds + (wm << 14) + fr * 128;
  const char* bw = lds + 32768 + ((wn >> 1) << 14) + ((wn & 1) << 13) + fr * 128;

  auto STG = [&](int nof, int H, int u) {
    char* L = lds + nof + (H << 14) + tid * 16;
    const size_t rs = (H < 2) ? lda2 : ldb2;
    const char* src = ((H < 2) ? Ab : Bb) + (size_t)((H & 1) * 128) * rs + (size_t)u * 128;
    gl_lds16(src, L);
    gl_lds16(src + 64 * rs, L + 8192);
  };

  bf16x8 aA[4], aB[4], bA[4], bB[4];
  f32x4 acc[8][4] = {};
  const int NT = K >> 6;

  STG(0, 0, 0); STG(0, 1, 0); STG(0, 2, 0); STG(0, 3, 0);
  STG(65536, 0, 1); STG(65536, 1, 1); STG(65536, 2, 1); STG(65536, 3, 1);
  VMC(8);
  __builtin_amdgcn_s_barrier();
  LDA_(aA, 0, axor0, 0);
  LDB_(bA, 0, axor0);

  for (int u = 0; u < NT; ++u) {
    const int dof = (u & 1) << 16;
    const int nof = dof ^ 65536;
    const bool stg = (u >= 1) & (u + 1 < NT);
    LDA_(aB, dof, axor0, 1);
    if (stg) { STG(nof, 0, u + 1); STG(nof, 1, u + 1); }
    LGKM(4);
    MFMAQ(0, aA, bA);
    LDA_(aA, dof, axor1, 0);
    LDB_(bB, dof, axor1);
    if (stg) { STG(nof, 2, u + 1); STG(nof, 3, u + 1); }
    LGKM(8);
    MFMAQ(1, aB, bA);
    LDA_(aB, dof, axor1, 1);
    LGKM(4);
    MFMAQ(0, aA, bB);
    LGKM(0);
    if (u + 1 < NT) {
      VMC(0);
      __builtin_amdgcn_s_barrier();
      LDA_(aA, nof, axor0, 0);
      LDB_(bA, nof, axor0);
    }
    MFMAQ(1, aB, bB);
  }

  char* C = (char*)C_ + (size_t)z * sC * ((EPI == EPI_F32) ? 4 : 2);
#pragma unroll
  for (int ni = 0; ni < 4; ++ni) {
    const int col = n0 + wn * 64 + ni * 16 + fr;
    float bcol = 0.f, scale = 0.f, shift = 0.f;
    if (EPI != EPI_BF16) bcol = bias_[col];
    if (EPI == EPI_BNPRELU) {
      scale = bn_g[col] * rsqrtf(bn_v[col] + EPSf);
      shift = bn_b[col] - bn_m[col] * scale;
    }
#pragma unroll
    for (int mi = 0; mi < 8; ++mi) {
      const int rb = m0 + wm * 128 + mi * 16 + kg * 4;
#pragma unroll
      for (int j = 0; j < 4; ++j) {
        const int row = rb + j;
        float v = acc[mi][ni][j] * alpha + bcol;
        if (EPI == EPI_F32) {
          ((float*)C)[(size_t)row * ldc + col] = v;
        } else if (EPI == EPI_BF16) {
          ((__hip_bfloat16*)C)[(size_t)row * ldc + col] = __float2bfloat16(v);
        } else {
          v = v * scale + shift;
          const float aa = pa[(size_t)(row & (Sd - 1)) * Fd + col];
          v = v > 0.f ? v : aa * v;
          ((__hip_bfloat16*)C)[(size_t)row * ldc + col] = __float2bfloat16(v);
        }
      }
    }
  }
}

// ---- m97-structure BT-GEMM (mha/FF3/folding) ----
template <int EPI>
__global__ __launch_bounds__(256, 2) void bt_gemm(
    const __hip_bfloat16* __restrict__ A_, int lda, size_t sA1, size_t sA2,
    const __hip_bfloat16* __restrict__ B_, int ldb, size_t sB1, size_t sB2,
    const float* __restrict__ bias_, size_t sBi1, size_t sBi2,
    void* __restrict__ C_, int ldc, size_t sC1, size_t sC2,
    int K, float alpha, int zshift,
    const float* __restrict__ bn_g, const float* __restrict__ bn_b,
    const float* __restrict__ bn_m, const float* __restrict__ bn_v,
    const float* __restrict__ pa) {
  __shared__ __hip_bfloat16 As[BM * BK];
  __shared__ __hip_bfloat16 Bs[BN * BK];

  const int tid = threadIdx.x;
  const int z = blockIdx.z;
  const int z1 = z >> zshift;
  const int z2 = z & ((1 << zshift) - 1);
  const int m0 = blockIdx.y * BM;
  const int n0 = blockIdx.x * BN;

  const __hip_bfloat16* A = A_ + (size_t)z1 * sA1 + (size_t)z2 * sA2;
  const __hip_bfloat16* Bt = B_ + (size_t)z1 * sB1 + (size_t)z2 * sB2;
  const float* bi = bias_ ? bias_ + (size_t)z1 * sBi1 + (size_t)z2 * sBi2 : nullptr;

  const int lane = tid & 63;
  const int wv = tid >> 6;
  const int wm = (wv >> 1) * 64;
  const int wn = (wv & 1) * 64;
  const int fr = lane & 15;
  const int kg = lane >> 4;

  const int srow = tid >> 2, sch = tid & 3;
  const size_t ldab = (size_t)lda * 2, ldbb = (size_t)ldb * 2;
  const char* Ap = (const char*)A + (size_t)(m0 + srow) * ldab + sch * 16;
  const char* Ap2 = Ap + 64 * ldab;
  const char* Bp = (const char*)Bt + (size_t)(n0 + srow) * ldbb + sch * 16;
  const char* Bp2 = Bp + 64 * ldbb;
  char* lA = (char*)As + tid * 16;
  char* lB = (char*)Bs + tid * 16;

  f32x4 acc[4][4] = {};

  for (int kt = 0; kt < K; kt += BK) {
    const size_t kb = (size_t)kt * 2;
    gl_lds16(Ap + kb, lA);
    gl_lds16(Ap2 + kb, lA + 4096);
    gl_lds16(Bp + kb, lB);
    gl_lds16(Bp2 + kb, lB + 4096);
    __syncthreads();

    bf16x8 afr[4], bfr[4];
#pragma unroll
    for (int mi = 0; mi < 4; ++mi)
      afr[mi] = *reinterpret_cast<const bf16x8*>(As + (wm + mi * 16 + fr) * BK + kg * 8);
#pragma unroll
    for (int ni = 0; ni < 4; ++ni)
      bfr[ni] = *reinterpret_cast<const bf16x8*>(Bs + (wn + ni * 16 + fr) * BK + kg * 8);
#pragma unroll
    for (int mi = 0; mi < 4; ++mi)
#pragma unroll
      for (int ni = 0; ni < 4; ++ni)
        acc[mi][ni] = __builtin_amdgcn_mfma_f32_16x16x32_bf16(afr[mi], bfr[ni], acc[mi][ni], 0, 0, 0);
    __syncthreads();
  }

  char* C = (char*)C_ + ((size_t)z1 * sC1 + (size_t)z2 * sC2) * ((EPI == EPI_F32) ? 4 : 2);
#pragma unroll
  for (int ni = 0; ni < 4; ++ni) {
    const int col = n0 + wn + ni * 16 + fr;
    float bcol = 0.f, scale = 0.f, shift = 0.f;
    if (bi) bcol = bi[col];
    if (EPI == EPI_BNPRELU) {
      scale = bn_g[col] * rsqrtf(bn_v[col] + EPSf);
      shift = bn_b[col] - bn_m[col] * scale;
    }
#pragma unroll
    for (int mi = 0; mi < 4; ++mi) {
      const int rb = m0 + wm + mi * 16 + kg * 4;
#pragma unroll
      for (int j = 0; j < 4; ++j) {
        const int row = rb + j;
        float v = acc[mi][ni][j] * alpha + bcol;
        if (EPI == EPI_F32) {
          ((float*)C)[(size_t)row * ldc + col] = v;
        } else if (EPI == EPI_BF16) {
          ((__hip_bfloat16*)C)[(size_t)row * ldc + col] = __float2bfloat16(v);
        } else {
          v = v * scale + shift;
          const float a = pa[(size_t)(row & (Sd - 1)) * Fd + col];
          v = v > 0.f ? v : a * v;
          ((__hip_bfloat16*)C)[(size_t)row * ldc + col] = __float2bfloat16(v);
        }
      }
    }
  }
}

// ---- transpose + convert: src [K][N] f32 -> dst [N][Kfull] bf16 ----
__global__ __launch_bounds__(256) void tconv(const float* __restrict__ src,
                                             __hip_bfloat16* __restrict__ dst,
                                             int N, int Kfull, size_t sIn, size_t sOut) {
  __shared__ __hip_bfloat16 t[64][65];
  const float* s = src + (size_t)blockIdx.z * sIn;
  __hip_bfloat16* d = dst + (size_t)blockIdx.z * sOut;
  const int k0 = blockIdx.y * 64, n0 = blockIdx.x * 64;
  const int tid = threadIdx.x;
#pragma unroll
  for (int i = 0; i < 4; ++i) {
    int slot = tid + i * 256;
    int r = slot >> 4, c = (slot & 15) * 4;
    const float4 v = *reinterpret_cast<const float4*>(s + (size_t)(k0 + r) * N + n0 + c);
    t[c + 0][r] = __float2bfloat16(v.x);
    t[c + 1][r] = __float2bfloat16(v.y);
    t[c + 2][r] = __float2bfloat16(v.z);
    t[c + 3][r] = __float2bfloat16(v.w);
  }
  __syncthreads();
#pragma unroll
  for (int i = 0; i < 2; ++i) {
    int slot = tid + i * 256;
    int n = slot >> 3, kc = (slot & 7) * 8;
    __hip_bfloat16 tmp[8];
#pragma unroll
    for (int j = 0; j < 8; ++j) tmp[j] = t[n][kc + j];
    *reinterpret_cast<float4*>(d + (size_t)(n0 + n) * Kfull + k0 + kc) =
        *reinterpret_cast<const float4*>(tmp);
  }
}

// ---- f32 -> bf16 elementwise; grid (nblk, ntensors), 8 elems/thread ----
__global__ __launch_bounds__(256) void conv3(const float* __restrict__ s0, const float* __restrict__ s1,
                                             const float* __restrict__ s2,
                                             __hip_bfloat16* __restrict__ d0, __hip_bfloat16* __restrict__ d1,
                                             __hip_bfloat16* __restrict__ d2) {
  const float* s = blockIdx.y == 0 ? s0 : (blockIdx.y == 1 ? s1 : s2);
  __hip_bfloat16* d = blockIdx.y == 0 ? d0 : (blockIdx.y == 1 ? d1 : d2);
  const size_t i = (size_t)blockIdx.x * 256 + threadIdx.x;
  const float4 a = reinterpret_cast<const float4*>(s)[2 * i];
  const float4 b = reinterpret_cast<const float4*>(s)[2 * i + 1];
  __hip_bfloat16 tmp[8] = {
      __float2bfloat16(a.x), __float2bfloat16(a.y), __float2bfloat16(a.z), __float2bfloat16(a.w),
      __float2bfloat16(b.x), __float2bfloat16(b.y), __float2bfloat16(b.z), __float2bfloat16(b.w)};
  *reinterpret_cast<float4*>(d + 8 * i) = *reinterpret_cast<const float4*>(tmp);
}

// ---- reductions ----
__device__ inline float wave_sum(float v) {
#pragma unroll
  for (int o = 32; o > 0; o >>= 1) v += __shfl_xor(v, o);
  return v;
}

__device__ inline float b2f(unsigned short u) {
  unsigned x = ((unsigned)u) << 16; float f; __builtin_memcpy(&f, &x, 4); return f;
}

// t1[hd] = sum_e WQ[h][d][e]*bK[h][e] (y=0); t2[hd] = sum_e WK[h][d][e]*bQ[h][e] (y=1)
__global__ __launch_bounds__(256) void tvec(const float* __restrict__ WQ, const float* __restrict__ bK,
                                            const float* __restrict__ WK, const float* __restrict__ bQ,
                                            float* __restrict__ t1, float* __restrict__ t2) {
  const float* W = blockIdx.y == 0 ? WQ : WK;
  const float* bb = blockIdx.y == 0 ? bK : bQ;
  float* out = blockIdx.y == 0 ? t1 : t2;
  const int wv = threadIdx.x >> 6, lane = threadIdx.x & 63;
  const int hd = blockIdx.x * 4 + wv;
  const int h = hd >> 9;
  float acc = 0.f;
#pragma unroll
  for (int j = 0; j < 8; ++j) {
    const int e = lane + 64 * j;
    acc += W[(size_t)hd * 512 + e] * bb[h * 512 + e];
  }
  acc = wave_sum(acc);
  if (lane == 0) out[hd] = acc;
}

// u[h][row] = Q[row]·t1[h], w[h][row] = K[row]·t2[h]. grid (8192), 256 thr.
__global__ __launch_bounds__(256) void uw_kernel(const float* __restrict__ Q, const float* __restrict__ K,
                                                 const float* __restrict__ t1, const float* __restrict__ t2,
                                                 float* __restrict__ u, float* __restrict__ w) {
  const int tid = threadIdx.x;
  const size_t row = blockIdx.x;
  const float2 q = reinterpret_cast<const float2*>(Q + row * 512)[tid];
  const float2 k = reinterpret_cast<const float2*>(K + row * 512)[tid];
  const int c = tid * 2;
  __shared__ float redu[8][4], redw[8][4];
  const int wv = tid >> 6;
#pragma unroll
  for (int h = 0; h < 8; ++h) {
    float ua = q.x * t1[h * 512 + c] + q.y * t1[h * 512 + c + 1];
    float wa = k.x * t2[h * 512 + c] + k.y * t2[h * 512 + c + 1];
    ua = wave_sum(ua);
    wa = wave_sum(wa);
    if ((tid & 63) == 0) { redu[h][wv] = ua; redw[h][wv] = wa; }
  }
  __syncthreads();
  if (tid < 8)
    u[tid * 8192 + row] = redu[tid][0] + redu[tid][1] + redu[tid][2] + redu[tid][3];
  else if (tid < 16)
    w[(tid - 8) * 8192 + row] = redw[tid - 8][0] + redw[tid - 8][1] + redw[tid - 8][2] + redw[tid - 8][3];
}

// c[h] = bQ[h]·bK[h]. grid (8), 256 thr.
__global__ __launch_bounds__(256) void cvec(const float* __restrict__ bQ, const float* __restrict__ bK,
                                            float* __restrict__ c) {
  const int h = blockIdx.x, tid = threadIdx.x;
  const float2 a = reinterpret_cast<const float2*>(bQ + h * 512)[tid];
  const float2 b = reinterpret_cast<const float2*>(bK + h * 512)[tid];
  float acc = wave_sum(a.x * b.x + a.y * b.y);
  __shared__ float red[4];
  if ((tid & 63) == 0) red[tid >> 6] = acc;
  __syncthreads();
  if (tid == 0) c[h] = red[0] + red[1] + red[2] + red[3];
}

// bvo[e] = bo[e] + sum_hd wot[e][hd]*bV[hd]. grid (128), 256 thr.
__global__ __launch_bounds__(256) void bvo_kernel(const __hip_bfloat16* __restrict__ wot,
                                                  const float* __restrict__ bV,
                                                  const float* __restrict__ bo,
                                                  float* __restrict__ bvo) {
  const int wv = threadIdx.x >> 6, lane = threadIdx.x & 63;
  const int e = blockIdx.x * 4 + wv;
  float acc = 0.f;
#pragma unroll
  for (int j = 0; j < 64; ++j) {
    const int hd = lane + 64 * j;
    acc += b2f(*(const unsigned short*)&wot[(size_t)e * 4096 + hd]) * bV[hd];
  }
  acc = wave_sum(acc);
  if (lane == 0) bvo[e] = bo[e] + acc;
}

// out = LN(Xa + Xb + Xc + cb[col])*gamma + beta (rows of 512). grid(8192), 256 thr.
__global__ __launch_bounds__(256) void add_ln3(const float* __restrict__ Xa, const float* __restrict__ Xb,
                                               const float* __restrict__ Xc, const float* __restrict__ cb,
                                               const float* __restrict__ gamma, const float* __restrict__ beta,
                                               float* __restrict__ out, __hip_bfloat16* __restrict__ outb) {
  const int tid = threadIdx.x;
  const size_t base = (size_t)blockIdx.x * Dd;
  const float2 a = reinterpret_cast<const float2*>(Xa + base)[tid];
  const float2 b = reinterpret_cast<const float2*>(Xb + base)[tid];
  const float2 c2 = reinterpret_cast<const float2*>(Xc + base)[tid];
  const int c = tid * 2;
  const float r0 = a.x + b.x + c2.x + cb[c];
  const float r1 = a.y + b.y + c2.y + cb[c + 1];
  float s = wave_sum(r0 + r1);
  float q = wave_sum(r0 * r0 + r1 * r1);
  __shared__ float rs[4], rq[4];
  if ((tid & 63) == 0) { rs[tid >> 6] = s; rq[tid >> 6] = q; }
  __syncthreads();
  const float mean = (rs[0] + rs[1] + rs[2] + rs[3]) * (1.f / Dd);
  const float msq = (rq[0] + rq[1] + rq[2] + rq[3]) * (1.f / Dd);
  const float inv = rsqrtf(msq - mean * mean + EPSf);
  const float y0 = (r0 - mean) * inv * gamma[c] + beta[c];
  const float y1 = (r1 - mean) * inv * gamma[c + 1] + beta[c + 1];
  out[base + c] = y0;
  out[base + c + 1] = y1;
  if (outb) {
    outb[base + c] = __float2bfloat16(y0);
    outb[base + c + 1] = __float2bfloat16(y1);
  }
}

extern "C" void kernel_launch(void* const* d_in, const int* in_sizes, int n_in,
                              void* d_out, int out_size, void* d_ws, size_t ws_size,
                              hipStream_t stream) {
  const float* Q = (const float*)d_in[0];
  const float* K = (const float*)d_in[1];
  const float* V = (const float*)d_in[2];
  const float* WQ = (const float*)d_in[3];
  const float* bQ = (const float*)d_in[4];
  const float* WK = (const float*)d_in[5];
  const float* bK = (const float*)d_in[6];
  const float* WV = (const float*)d_in[7];
  const float* bV = (const float*)d_in[8];
  const float* Wo = (const float*)d_in[9];
  const float* bo = (const float*)d_in[10];
  const float* W0 = (const float*)d_in[11];
  const float* b0 = (const float*)d_in[12];
  const float* g0 = (const float*)d_in[13];
  const float* be0 = (const float*)d_in[14];
  const float* m0 = (const float*)d_in[15];
  const float* v0 = (const float*)d_in[16];
  const float* a0 = (const float*)d_in[17];
  const float* W1 = (const float*)d_in[18];
  const float* b1 = (const float*)d_in[19];
  const float* g1 = (const float*)d_in[20];
  const float* be1 = (const float*)d_in[21];
  const float* m1 = (const float*)d_in[22];
  const float* v1 = (const float*)d_in[23];
  const float* a1 = (const float*)d_in[24];
  const float* W2 = (const float*)d_in[25];
  const float* b2 = (const float*)d_in[26];
  const float* ln0g = (const float*)d_in[27];
  const float* ln0b = (const float*)d_in[28];
  const float* ln1g = (const float*)d_in[29];
  const float* ln1b = (const float*)d_in[30];

  typedef __hip_bfloat16 bf;
  const size_t MB = 1u << 20;
  const size_t KB = 1u << 10;
  char* ws = (char*)d_ws;
  // -------- attention layout (peak 120 MiB) --------
  bf* PR = (bf*)(ws);                      // [8192][4096]  0..64M   P, then R in place
  bf* wot = (bf*)(ws + 64 * MB);           // [512][4096]   64..68M  (pre-loop only)
  bf* wqbf = (bf*)(ws + 68 * MB);          // [8][512][512] 68..72M
  bf* wkbf = (bf*)(ws + 72 * MB);          // 72..76M
  bf* wvbf = (bf*)(ws + 76 * MB);          // 76..80M
  bf* wqkt = (bf*)(ws + 80 * MB);          // 80..84M (P only)
  bf* kbf = (bf*)(ws + 96 * MB);           // [8192][512]   96..104M
  bf* vbft = (bf*)(ws + 104 * MB);         // [8][512][1024] 104..112M
  bf* qbf = (bf*)(ws + 112 * MB);          // [8192][512]   112..120M (dead after P)
  bf* wvot = (bf*)(ws + 112 * MB);         // [512][4096]   112..116M (after P)
  float* u = (float*)(ws + 116 * MB);                 // [8][8192] 256K
  float* w = (float*)(ws + 116 * MB + 256 * KB);      // 256K
  float* t1 = (float*)(ws + 116 * MB + 768 * KB);     // [8][512]
  float* t2 = (float*)(ws + 116 * MB + 784 * KB);
  float* cv = (float*)(ws + 116 * MB + 800 * KB);     // [8]
  float* bvo = (float*)(ws + 116 * MB + 804 * KB);    // [512]
  // -------- post-attention (dead-region reuse, stream-order audited) --------
  float* mhap = (float*)(ws + 64 * MB);    // 2x[8192][512] f32 partials 64..96M
  float* xbuf = (float*)(ws);              // [8192][512] f32  0..16M (over R, dead after mha)
  bf* xb = (bf*)(ws + 16 * MB);            // [8192][512] bf16 16..24M
  bf* h0 = (bf*)(ws + 24 * MB);            // [8192][2048] 24..56M
  bf* h1 = (bf*)(ws + 56 * MB);            // [8192][2048] 56..88M (over mhap, dead after LN0)
  float* ffp = (float*)(ws + 24 * MB);     // 2x[8192][512] f32 partials 24..56M (over h0)
  bf* w0t = (bf*)(ws + 96 * MB);           // [2048][512]  96..98M  (over kbf, dead)
  bf* w1t = (bf*)(ws + 98 * MB);           // [2048][2048] 98..106M
  bf* w2t = (bf*)(ws + 106 * MB);          // [512][2048]  106..108M

  const size_t SD = (size_t)Sd * Dd;       // 524288
  const size_t DD = (size_t)Dd * Dd;       // 262144
  const size_t SDH = (size_t)Sd * Hd * Dd; // 4194304
  const float* np = nullptr;

  // ---- conversions ----
  conv3<<<dim3(2048, 2), 256, 0, stream>>>(Q, K, K, qbf, kbf, kbf);
  conv3<<<dim3(1024, 3), 256, 0, stream>>>(WQ, WK, WV, wqbf, wkbf, wvbf);
  tconv<<<dim3(8, 16, 8), 256, 0, stream>>>(V, vbft, Dd, Sd, SD, SD);
  tconv<<<dim3(8, 64, 1), 256, 0, stream>>>(Wo, wot, Dd, Hd * Dd, 0, 0);

  // ---- wqkt fold + P (while qbf alive) ----
  bt_gemm<EPI_BF16><<<dim3(4, 4, 8), 256, 0, stream>>>(
      wkbf, Dd, 0, DD, wqbf, Dd, 0, DD, np, 0, 0,
      wqkt, Dd, 0, DD, Dd, 1.f, 3, np, np, np, np, np);
  big_gemm<EPI_BF16><<<dim3(16, 32, 1), 512, 0, stream>>>(
      qbf, Dd, 0, 0, wqkt, 0, np, PR, Hd * Dd, 0, Dd, 1.f, np, np, np, np, np);

  // ---- remaining precompute (qbf region now dead) ----
  bt_gemm<EPI_BF16><<<dim3(4, 4, 8), 256, 0, stream>>>(
      wot, Hd * Dd, 0, 512, wvbf, Dd, 0, DD, np, 0, 0,
      wvot, Hd * Dd, 0, 512, Dd, 1.f, 3, np, np, np, np, np);
  tvec<<<dim3(1024, 2), 256, 0, stream>>>(WQ, bK, WK, bQ, t1, t2);
  uw_kernel<<<Bd * Sd, 256, 0, stream>>>(Q, K, t1, t2, u, w);
  cvec<<<8, 256, 0, stream>>>(bQ, bK, cv);
  bvo_kernel<<<128, 256, 0, stream>>>(wot, bV, bo, bvo);

  // ---- fused attention middle: one launch, in-place P -> R ----
  attn_fused<<<dim3(32, 64), 512, 0, stream>>>(PR, kbf, vbft, u, w, cv);

  // ---- mha partials: split-K (z=half) ----
  bt_gemm<EPI_F32><<<dim3(4, 64, 2), 256, 0, stream>>>(
      PR, Hd * Dd, 2048, 0, wvot, Hd * Dd, 2048, 0, np, 0, 0,
      mhap, Dd, SDH, 0, 2048, 1.f, 0, np, np, np, np, np);
  add_ln3<<<Bd * Sd, 256, 0, stream>>>(Q, mhap, mhap + SDH, bvo, ln0g, ln0b, xbuf, xb);

  // ---- FF ----
  tconv<<<dim3(32, 8, 1), 256, 0, stream>>>(W0, w0t, Fd, Dd, 0, 0);
  tconv<<<dim3(32, 32, 1), 256, 0, stream>>>(W1, w1t, Fd, Fd, 0, 0);
  tconv<<<dim3(8, 32, 1), 256, 0, stream>>>(W2, w2t, Dd, Fd, 0, 0);

  big_gemm<EPI_BNPRELU><<<dim3(8, 32, 1), 512, 0, stream>>>(
      xb, Dd, 0, 0, w0t, 0, b0, h0, Fd, 0, Dd, 1.f, g0, be0, m0, v0, a0);
  big_gemm<EPI_BNPRELU><<<dim3(8, 32, 1), 512, 0, stream>>>(
      h0, Fd, 0, 0, w1t, 0, b1, h1, Fd, 0, Fd, 1.f, g1, be1, m1, v1, a1);
  bt_gemm<EPI_F32><<<dim3(4, 64, 2), 256, 0, stream>>>(
      h1, Fd, 1024, 0, w2t, Fd, 1024, 0, np, 0, 0,
      ffp, Dd, SDH, 0, 1024, 1.f, 0, np, np, np, np, np);
  add_ln3<<<Bd * Sd, 256, 0, stream>>>(xbuf, ffp, ffp + SDH, b2, ln1g, ln1b, (float*)d_out, nullptr);
}

// Round 14
// 661.891 us; speedup vs baseline: 1.6814x; 1.6814x over previous
//
#include <hip/hip_runtime.h>
#include <hip/hip_bf16.h>
#include <cstdint>
#include <cstddef>

#define Sd 1024
#define Dd 512
#define Hd 8
#define Fd 2048
#define Bd 8
#define EPSf 1e-3f

typedef __bf16 bf16x8 __attribute__((ext_vector_type(8)));
typedef float f32x4 __attribute__((ext_vector_type(4)));
typedef __attribute__((address_space(3))) unsigned int lds_u32;
typedef __attribute__((address_space(1))) const unsigned int gl_u32;

#define BM 128
#define BN 128
#define BK 32

enum { EPI_BF16 = 0, EPI_F32 = 1, EPI_BNPRELU = 2, EPI_SCORES = 3, EPI_PV = 4 };

__device__ __forceinline__ void gl_lds16(const void* g, void* l) {
  __builtin_amdgcn_global_load_lds((gl_u32*)g, (lds_u32*)l, 16, 0, 0);
}

// ======================================================================
// 256x256 GEMM (frozen R6 core): counted-lgkmcnt pipeline.
// C[M,N] = epi(alpha * A @ Bt^T + bias). See R10 comments.
// ======================================================================

#define LGKM(n)                                                  \
  asm volatile("s_waitcnt lgkmcnt(" #n ")" ::: "memory");        \
  __builtin_amdgcn_sched_barrier(0)
#define VMC(n) asm volatile("s_waitcnt vmcnt(" #n ")" ::: "memory")

#define LDA_(dst, dof, xr, mh)                                               \
  _Pragma("unroll") for (int i_ = 0; i_ < 4; ++i_)                           \
      dst[i_] = *(const bf16x8*)(aw + (dof) + (xr) + (mh) * 8192 + i_ * 2048);
#define LDB_(dst, dof, xr)                                                   \
  _Pragma("unroll") for (int i_ = 0; i_ < 4; ++i_)                           \
      dst[i_] = *(const bf16x8*)(bw + (dof) + (xr) + i_ * 2048);
#define MFMAQ(q, av, bv)                                                     \
  __builtin_amdgcn_s_setprio(1);                                             \
  {                                                                          \
    _Pragma("unroll") for (int i_ = 0; i_ < 4; ++i_) {                       \
      _Pragma("unroll") for (int n_ = 0; n_ < 4; ++n_)                       \
          acc[(q) * 4 + i_][n_] = __builtin_amdgcn_mfma_f32_16x16x32_bf16(   \
              av[i_], bv[n_], acc[(q) * 4 + i_][n_], 0, 0, 0);               \
    }                                                                        \
  }                                                                          \
  __builtin_amdgcn_s_setprio(0)

template <int EPI>
__global__ __launch_bounds__(512, 2) void big_gemm(
    const __hip_bfloat16* __restrict__ A_, int lda, size_t sA1, size_t sA2,
    const __hip_bfloat16* __restrict__ B_, size_t sB1,
    const float* __restrict__ bias_,
    void* __restrict__ C_, int ldc, size_t sC, int K, float alpha,
    const float* __restrict__ bn_g, const float* __restrict__ bn_b,
    const float* __restrict__ bn_m, const float* __restrict__ bn_v,
    const float* __restrict__ pa) {
  __shared__ __align__(16) char lds[131072];
  const int tid = threadIdx.x;
  const int gx = gridDim.x;
  int bx, by, z;
  if (EPI == EPI_SCORES) {
    // z-slice -> XCD affinity (gz % 8 == 0 required; scores gz=16)
    const int id = blockIdx.x + gx * (blockIdx.y + gridDim.y * blockIdx.z);
    const int bps = gx * gridDim.y;            // blocks per z-slice
    const int xcd = id & 7, slot = id >> 3;
    const int sl = slot / bps, inner = slot % bps;
    z = xcd + 8 * sl;
    bx = inner % gx;
    by = inner / gx;
  } else {
    const int nwg = gx * gridDim.y;
    const int orig = blockIdx.y * gx + blockIdx.x;
    const int wgid = (orig & 7) * (nwg >> 3) + (orig >> 3);
    bx = wgid % gx;
    by = wgid / gx;
    z = blockIdx.z;
  }
  const int m0 = by * 256, n0 = bx * 256;
  const int z1 = z >> 3, z2 = z & 7;

  const int lane = tid & 63;
  const int wid = tid >> 6;
  const int wm = wid >> 2;
  const int wn = wid & 3;
  const int fr = lane & 15;
  const int kg = lane >> 4;

  const int r0 = tid >> 3;
  const int c0 = (tid & 7) ^ (r0 & 7);
  const size_t lda2 = (size_t)lda * 2;
  const size_t ldb2 = (size_t)K * 2;
  const char* Ab = (const char*)(A_ + (size_t)z1 * sA1 + (size_t)z2 * sA2) +
                   (size_t)(m0 + r0) * lda2 + c0 * 16;
  const char* Bb = (const char*)(B_ + (size_t)z1 * sB1) + (size_t)(n0 + r0) * ldb2 + c0 * 16;

  const int axor0 = (kg ^ (fr & 7)) << 4;
  const int axor1 = ((4 + kg) ^ (fr & 7)) << 4;
  const char* aw = lds + (wm << 14) + fr * 128;
  const char* bw = lds + 32768 + ((wn >> 1) << 14) + ((wn & 1) << 13) + fr * 128;

  auto STG = [&](int nof, int H, int u) {  // H: 0=A0 1=A1 2=B0 3=B1
    char* L = lds + nof + (H << 14) + tid * 16;
    const size_t rs = (H < 2) ? lda2 : ldb2;
    const char* src = ((H < 2) ? Ab : Bb) + (size_t)((H & 1) * 128) * rs + (size_t)u * 128;
    gl_lds16(src, L);
    gl_lds16(src + 64 * rs, L + 8192);
  };

  bf16x8 aA[4], aB[4], bA[4], bB[4];
  f32x4 acc[8][4] = {};
  const int NT = K >> 6;

  STG(0, 0, 0); STG(0, 1, 0); STG(0, 2, 0); STG(0, 3, 0);
  STG(65536, 0, 1); STG(65536, 1, 1); STG(65536, 2, 1); STG(65536, 3, 1);
  VMC(8);
  __builtin_amdgcn_s_barrier();
  LDA_(aA, 0, axor0, 0);
  LDB_(bA, 0, axor0);

  for (int u = 0; u < NT; ++u) {
    const int dof = (u & 1) << 16;
    const int nof = dof ^ 65536;
    const bool stg = (u >= 1) & (u + 1 < NT);
    LDA_(aB, dof, axor0, 1);
    if (stg) { STG(nof, 0, u + 1); STG(nof, 1, u + 1); }
    LGKM(4);
    MFMAQ(0, aA, bA);
    LDA_(aA, dof, axor1, 0);
    LDB_(bB, dof, axor1);
    if (stg) { STG(nof, 2, u + 1); STG(nof, 3, u + 1); }
    LGKM(8);
    MFMAQ(1, aB, bA);
    LDA_(aB, dof, axor1, 1);
    LGKM(4);
    MFMAQ(0, aA, bB);
    LGKM(0);
    if (u + 1 < NT) {
      VMC(0);
      __builtin_amdgcn_s_barrier();
      LDA_(aA, nof, axor0, 0);
      LDB_(bA, nof, axor0);
    }
    MFMAQ(1, aB, bB);
  }

  // epilogue: C/D layout col=lane&15, row=(lane>>4)*4+j [m89-verified]
  char* C = (char*)C_ + (size_t)z * sC * ((EPI == EPI_F32) ? 4 : 2);
  if (EPI == EPI_SCORES) {
    const float cvv = bn_m[z2];
    const float* ub = bn_g + (size_t)z2 * 8192 + (size_t)z1 * 1024;
    const float* wb = bn_b + (size_t)z2 * 8192 + (size_t)z1 * 1024;
    float* rs = (float*)bn_v + ((size_t)z << 10);
    float wc[4];
#pragma unroll
    for (int ni = 0; ni < 4; ++ni) wc[ni] = wb[n0 + wn * 64 + ni * 16 + fr];
#pragma unroll
    for (int mi = 0; mi < 8; ++mi) {
      const int rb = m0 + wm * 128 + mi * 16 + kg * 4;
      float rowa[4] = {0.f, 0.f, 0.f, 0.f};
#pragma unroll
      for (int ni = 0; ni < 4; ++ni) {
        const int col = n0 + wn * 64 + ni * 16 + fr;
#pragma unroll
        for (int j = 0; j < 4; ++j) {
          const int row = rb + j;
          const float e = __expf((acc[mi][ni][j] + ub[row] + wc[ni] + cvv) * alpha);
          rowa[j] += e;
          ((__hip_bfloat16*)C)[(size_t)row * ldc + col] = __float2bfloat16(e);
        }
      }
#pragma unroll
      for (int j = 0; j < 4; ++j) {
        float v = rowa[j];
        v += __shfl_xor(v, 1);
        v += __shfl_xor(v, 2);
        v += __shfl_xor(v, 4);
        v += __shfl_xor(v, 8);
        if (fr == 0) atomicAdd(rs + rb + j, v);
      }
    }
  } else {
#pragma unroll
    for (int ni = 0; ni < 4; ++ni) {
      const int col = n0 + wn * 64 + ni * 16 + fr;
      float bcol = 0.f, scale = 0.f, shift = 0.f;
      if (EPI != EPI_BF16) bcol = bias_[col];
      if (EPI == EPI_BNPRELU) {
        scale = bn_g[col] * rsqrtf(bn_v[col] + EPSf);
        shift = bn_b[col] - bn_m[col] * scale;
      }
#pragma unroll
      for (int mi = 0; mi < 8; ++mi) {
        const int rb = m0 + wm * 128 + mi * 16 + kg * 4;
#pragma unroll
        for (int j = 0; j < 4; ++j) {
          const int row = rb + j;
          float v = acc[mi][ni][j] * alpha + bcol;
          if (EPI == EPI_F32) {
            ((float*)C)[(size_t)row * ldc + col] = v;
          } else if (EPI == EPI_BF16) {
            ((__hip_bfloat16*)C)[(size_t)row * ldc + col] = __float2bfloat16(v);
          } else {
            v = v * scale + shift;
            const float aa = pa[(size_t)(row & (Sd - 1)) * Fd + col];
            v = v > 0.f ? v : aa * v;
            ((__hip_bfloat16*)C)[(size_t)row * ldc + col] = __float2bfloat16(v);
          }
        }
      }
    }
  }
}

// ---- m97-structure BT-GEMM (PV/mha/FF3/folding) ----
// XCDZ=1: z-slice->XCD affinity block remap (requires gz%8==0).
template <int EPI, int XCDZ = 0>
__global__ __launch_bounds__(256, 2) void bt_gemm(
    const __hip_bfloat16* __restrict__ A_, int lda, size_t sA1, size_t sA2,
    const __hip_bfloat16* __restrict__ B_, int ldb, size_t sB1, size_t sB2,
    const float* __restrict__ bias_, size_t sBi1, size_t sBi2,
    void* __restrict__ C_, int ldc, size_t sC1, size_t sC2,
    int K, float alpha, int zshift,
    const float* __restrict__ bn_g, const float* __restrict__ bn_b,
    const float* __restrict__ bn_m, const float* __restrict__ bn_v,
    const float* __restrict__ pa) {
  __shared__ __hip_bfloat16 As[BM * BK];
  __shared__ __hip_bfloat16 Bs[BN * BK];

  const int tid = threadIdx.x;
  int bxq, byq, z;
  if (XCDZ) {
    const int gx = gridDim.x;
    const int id = blockIdx.x + gx * (blockIdx.y + gridDim.y * blockIdx.z);
    const int bps = gx * gridDim.y;
    const int xcd = id & 7, slot = id >> 3;
    const int sl = slot / bps, inner = slot % bps;
    z = xcd + 8 * sl;
    bxq = inner % gx;
    byq = inner / gx;
  } else {
    bxq = blockIdx.x;
    byq = blockIdx.y;
    z = blockIdx.z;
  }
  const int z1 = z >> zshift;
  const int z2 = z & ((1 << zshift) - 1);
  const int m0 = byq * BM;
  const int n0 = bxq * BN;

  const __hip_bfloat16* A = A_ + (size_t)z1 * sA1 + (size_t)z2 * sA2;
  const __hip_bfloat16* Bt = B_ + (size_t)z1 * sB1 + (size_t)z2 * sB2;
  const float* bi = bias_ ? bias_ + (size_t)z1 * sBi1 + (size_t)z2 * sBi2 : nullptr;

  const int lane = tid & 63;
  const int wv = tid >> 6;
  const int wm = (wv >> 1) * 64;
  const int wn = (wv & 1) * 64;
  const int fr = lane & 15;
  const int kg = lane >> 4;

  const int srow = tid >> 2, sch = tid & 3;
  const size_t ldab = (size_t)lda * 2, ldbb = (size_t)ldb * 2;
  const char* Ap = (const char*)A + (size_t)(m0 + srow) * ldab + sch * 16;
  const char* Ap2 = Ap + 64 * ldab;
  const char* Bp = (const char*)Bt + (size_t)(n0 + srow) * ldbb + sch * 16;
  const char* Bp2 = Bp + 64 * ldbb;
  char* lA = (char*)As + tid * 16;
  char* lB = (char*)Bs + tid * 16;

  f32x4 acc[4][4] = {};

  for (int kt = 0; kt < K; kt += BK) {
    const size_t kb = (size_t)kt * 2;
    gl_lds16(Ap + kb, lA);
    gl_lds16(Ap2 + kb, lA + 4096);
    gl_lds16(Bp + kb, lB);
    gl_lds16(Bp2 + kb, lB + 4096);
    __syncthreads();

    bf16x8 afr[4], bfr[4];
#pragma unroll
    for (int mi = 0; mi < 4; ++mi)
      afr[mi] = *reinterpret_cast<const bf16x8*>(As + (wm + mi * 16 + fr) * BK + kg * 8);
#pragma unroll
    for (int ni = 0; ni < 4; ++ni)
      bfr[ni] = *reinterpret_cast<const bf16x8*>(Bs + (wn + ni * 16 + fr) * BK + kg * 8);
#pragma unroll
    for (int mi = 0; mi < 4; ++mi)
#pragma unroll
      for (int ni = 0; ni < 4; ++ni)
        acc[mi][ni] = __builtin_amdgcn_mfma_f32_16x16x32_bf16(afr[mi], bfr[ni], acc[mi][ni], 0, 0, 0);
    __syncthreads();
  }

  char* C = (char*)C_ + ((size_t)z1 * sC1 + (size_t)z2 * sC2) * ((EPI == EPI_F32) ? 4 : 2);
  float rinv_[4][4];
  if (EPI == EPI_PV) {
#pragma unroll
    for (int mi = 0; mi < 4; ++mi)
#pragma unroll
      for (int j = 0; j < 4; ++j)
        rinv_[mi][j] = 1.0f / bn_v[((size_t)z << 10) + m0 + wm + mi * 16 + kg * 4 + j];
  }
#pragma unroll
  for (int ni = 0; ni < 4; ++ni) {
    const int col = n0 + wn + ni * 16 + fr;
    float bcol = 0.f, scale = 0.f, shift = 0.f;
    if (bi) bcol = bi[col];
    if (EPI == EPI_BNPRELU) {
      scale = bn_g[col] * rsqrtf(bn_v[col] + EPSf);
      shift = bn_b[col] - bn_m[col] * scale;
    }
#pragma unroll
    for (int mi = 0; mi < 4; ++mi) {
      const int rb = m0 + wm + mi * 16 + kg * 4;
#pragma unroll
      for (int j = 0; j < 4; ++j) {
        const int row = rb + j;
        if (EPI == EPI_PV) {
          ((__hip_bfloat16*)C)[(size_t)row * ldc + col] = __float2bfloat16(acc[mi][ni][j] * rinv_[mi][j]);
        } else {
          float v = acc[mi][ni][j] * alpha + bcol;
          if (EPI == EPI_F32) {
            ((float*)C)[(size_t)row * ldc + col] = v;
          } else if (EPI == EPI_BF16) {
            ((__hip_bfloat16*)C)[(size_t)row * ldc + col] = __float2bfloat16(v);
          } else {
            v = v * scale + shift;
            const float a = pa[(size_t)(row & (Sd - 1)) * Fd + col];
            v = v > 0.f ? v : a * v;
            ((__hip_bfloat16*)C)[(size_t)row * ldc + col] = __float2bfloat16(v);
          }
        }
      }
    }
  }
}

// ---- transpose + convert: src [K][N] f32 -> dst [N][Kfull] bf16 ----
__global__ __launch_bounds__(256) void tconv(const float* __restrict__ src,
                                             __hip_bfloat16* __restrict__ dst,
                                             int N, int Kfull, size_t sIn, size_t sOut) {
  __shared__ __hip_bfloat16 t[64][65];
  const float* s = src + (size_t)blockIdx.z * sIn;
  __hip_bfloat16* d = dst + (size_t)blockIdx.z * sOut;
  const int k0 = blockIdx.y * 64, n0 = blockIdx.x * 64;
  const int tid = threadIdx.x;
#pragma unroll
  for (int i = 0; i < 4; ++i) {
    int slot = tid + i * 256;
    int r = slot >> 4, c = (slot & 15) * 4;
    const float4 v = *reinterpret_cast<const float4*>(s + (size_t)(k0 + r) * N + n0 + c);
    t[c + 0][r] = __float2bfloat16(v.x);
    t[c + 1][r] = __float2bfloat16(v.y);
    t[c + 2][r] = __float2bfloat16(v.z);
    t[c + 3][r] = __float2bfloat16(v.w);
  }
  __syncthreads();
#pragma unroll
  for (int i = 0; i < 2; ++i) {
    int slot = tid + i * 256;
    int n = slot >> 3, kc = (slot & 7) * 8;
    __hip_bfloat16 tmp[8];
#pragma unroll
    for (int j = 0; j < 8; ++j) tmp[j] = t[n][kc + j];
    *reinterpret_cast<float4*>(d + (size_t)(n0 + n) * Kfull + k0 + kc) =
        *reinterpret_cast<const float4*>(tmp);
  }
}

// ---- f32 -> bf16 elementwise; grid (nblk, ntensors), 8 elems/thread ----
__global__ __launch_bounds__(256) void conv3(const float* __restrict__ s0, const float* __restrict__ s1,
                                             const float* __restrict__ s2,
                                             __hip_bfloat16* __restrict__ d0, __hip_bfloat16* __restrict__ d1,
                                             __hip_bfloat16* __restrict__ d2) {
  const float* s = blockIdx.y == 0 ? s0 : (blockIdx.y == 1 ? s1 : s2);
  __hip_bfloat16* d = blockIdx.y == 0 ? d0 : (blockIdx.y == 1 ? d1 : d2);
  const size_t i = (size_t)blockIdx.x * 256 + threadIdx.x;
  const float4 a = reinterpret_cast<const float4*>(s)[2 * i];
  const float4 b = reinterpret_cast<const float4*>(s)[2 * i + 1];
  __hip_bfloat16 tmp[8] = {
      __float2bfloat16(a.x), __float2bfloat16(a.y), __float2bfloat16(a.z), __float2bfloat16(a.w),
      __float2bfloat16(b.x), __float2bfloat16(b.y), __float2bfloat16(b.z), __float2bfloat16(b.w)};
  *reinterpret_cast<float4*>(d + 8 * i) = *reinterpret_cast<const float4*>(tmp);
}

// ---- reductions ----
__device__ inline float wave_sum(float v) {
#pragma unroll
  for (int o = 32; o > 0; o >>= 1) v += __shfl_xor(v, o);
  return v;
}

__device__ inline float b2f(unsigned short u) {
  unsigned x = ((unsigned)u) << 16; float f; __builtin_memcpy(&f, &x, 4); return f;
}

// t1[hd] = sum_e WQ[h][d][e]*bK[h][e] (y=0); t2[hd] = sum_e WK[h][d][e]*bQ[h][e] (y=1)
__global__ __launch_bounds__(256) void tvec(const float* __restrict__ WQ, const float* __restrict__ bK,
                                            const float* __restrict__ WK, const float* __restrict__ bQ,
                                            float* __restrict__ t1, float* __restrict__ t2) {
  const float* W = blockIdx.y == 0 ? WQ : WK;
  const float* bb = blockIdx.y == 0 ? bK : bQ;
  float* out = blockIdx.y == 0 ? t1 : t2;
  const int wv = threadIdx.x >> 6, lane = threadIdx.x & 63;
  const int hd = blockIdx.x * 4 + wv;
  const int h = hd >> 9;
  float acc = 0.f;
#pragma unroll
  for (int j = 0; j < 8; ++j) {
    const int e = lane + 64 * j;
    acc += W[(size_t)hd * 512 + e] * bb[h * 512 + e];
  }
  acc = wave_sum(acc);
  if (lane == 0) out[hd] = acc;
}

// u[h][row] = Q[row]·t1[h], w[h][row] = K[row]·t2[h]. grid (8192), 256 thr.
__global__ __launch_bounds__(256) void uw_kernel(const float* __restrict__ Q, const float* __restrict__ K,
                                                 const float* __restrict__ t1, const float* __restrict__ t2,
                                                 float* __restrict__ u, float* __restrict__ w) {
  const int tid = threadIdx.x;
  const size_t row = blockIdx.x;
  const float2 q = reinterpret_cast<const float2*>(Q + row * 512)[tid];
  const float2 k = reinterpret_cast<const float2*>(K + row * 512)[tid];
  const int c = tid * 2;
  __shared__ float redu[8][4], redw[8][4];
  const int wv = tid >> 6;
#pragma unroll
  for (int h = 0; h < 8; ++h) {
    float ua = q.x * t1[h * 512 + c] + q.y * t1[h * 512 + c + 1];
    float wa = k.x * t2[h * 512 + c] + k.y * t2[h * 512 + c + 1];
    ua = wave_sum(ua);
    wa = wave_sum(wa);
    if ((tid & 63) == 0) { redu[h][wv] = ua; redw[h][wv] = wa; }
  }
  __syncthreads();
  if (tid < 8)
    u[tid * 8192 + row] = redu[tid][0] + redu[tid][1] + redu[tid][2] + redu[tid][3];
  else if (tid < 16)
    w[(tid - 8) * 8192 + row] = redw[tid - 8][0] + redw[tid - 8][1] + redw[tid - 8][2] + redw[tid - 8][3];
}

// c[h] = bQ[h]·bK[h]. grid (8), 256 thr.
__global__ __launch_bounds__(256) void cvec(const float* __restrict__ bQ, const float* __restrict__ bK,
                                            float* __restrict__ c) {
  const int h = blockIdx.x, tid = threadIdx.x;
  const float2 a = reinterpret_cast<const float2*>(bQ + h * 512)[tid];
  const float2 b = reinterpret_cast<const float2*>(bK + h * 512)[tid];
  float acc = wave_sum(a.x * b.x + a.y * b.y);
  __shared__ float red[4];
  if ((tid & 63) == 0) red[tid >> 6] = acc;
  __syncthreads();
  if (tid == 0) c[h] = red[0] + red[1] + red[2] + red[3];
}

// bvo[e] = bo[e] + sum_hd wot[e][hd]*bV[hd]. grid (128), 256 thr.
__global__ __launch_bounds__(256) void bvo_kernel(const __hip_bfloat16* __restrict__ wot,
                                                  const float* __restrict__ bV,
                                                  const float* __restrict__ bo,
                                                  float* __restrict__ bvo) {
  const int wv = threadIdx.x >> 6, lane = threadIdx.x & 63;
  const int e = blockIdx.x * 4 + wv;
  float acc = 0.f;
#pragma unroll
  for (int j = 0; j < 64; ++j) {
    const int hd = lane + 64 * j;
    acc += b2f(*(const unsigned short*)&wot[(size_t)e * 4096 + hd]) * bV[hd];
  }
  acc = wave_sum(acc);
  if (lane == 0) bvo[e] = bo[e] + acc;
}

// out = LN(Xa + Xb + Xc + cb[col])*gamma + beta (rows of 512). grid(8192), 256 thr.
__global__ __launch_bounds__(256) void add_ln3(const float* __restrict__ Xa, const float* __restrict__ Xb,
                                               const float* __restrict__ Xc, const float* __restrict__ cb,
                                               const float* __restrict__ gamma, const float* __restrict__ beta,
                                               float* __restrict__ out, __hip_bfloat16* __restrict__ outb) {
  const int tid = threadIdx.x;
  const size_t base = (size_t)blockIdx.x * Dd;
  const float2 a = reinterpret_cast<const float2*>(Xa + base)[tid];
  const float2 b = reinterpret_cast<const float2*>(Xb + base)[tid];
  const float2 c2 = reinterpret_cast<const float2*>(Xc + base)[tid];
  const int c = tid * 2;
  const float r0 = a.x + b.x + c2.x + cb[c];
  const float r1 = a.y + b.y + c2.y + cb[c + 1];
  float s = wave_sum(r0 + r1);
  float q = wave_sum(r0 * r0 + r1 * r1);
  __shared__ float rs[4], rq[4];
  if ((tid & 63) == 0) { rs[tid >> 6] = s; rq[tid >> 6] = q; }
  __syncthreads();
  const float mean = (rs[0] + rs[1] + rs[2] + rs[3]) * (1.f / Dd);
  const float msq = (rq[0] + rq[1] + rq[2] + rq[3]) * (1.f / Dd);
  const float inv = rsqrtf(msq - mean * mean + EPSf);
  const float y0 = (r0 - mean) * inv * gamma[c] + beta[c];
  const float y1 = (r1 - mean) * inv * gamma[c + 1] + beta[c + 1];
  out[base + c] = y0;
  out[base + c + 1] = y1;
  if (outb) {
    outb[base + c] = __float2bfloat16(y0);
    outb[base + c + 1] = __float2bfloat16(y1);
  }
}

extern "C" void kernel_launch(void* const* d_in, const int* in_sizes, int n_in,
                              void* d_out, int out_size, void* d_ws, size_t ws_size,
                              hipStream_t stream) {
  const float* Q = (const float*)d_in[0];
  const float* K = (const float*)d_in[1];
  const float* V = (const float*)d_in[2];
  const float* WQ = (const float*)d_in[3];
  const float* bQ = (const float*)d_in[4];
  const float* WK = (const float*)d_in[5];
  const float* bK = (const float*)d_in[6];
  const float* WV = (const float*)d_in[7];
  const float* bV = (const float*)d_in[8];
  const float* Wo = (const float*)d_in[9];
  const float* bo = (const float*)d_in[10];
  const float* W0 = (const float*)d_in[11];
  const float* b0 = (const float*)d_in[12];
  const float* g0 = (const float*)d_in[13];
  const float* be0 = (const float*)d_in[14];
  const float* m0 = (const float*)d_in[15];
  const float* v0 = (const float*)d_in[16];
  const float* a0 = (const float*)d_in[17];
  const float* W1 = (const float*)d_in[18];
  const float* b1 = (const float*)d_in[19];
  const float* g1 = (const float*)d_in[20];
  const float* be1 = (const float*)d_in[21];
  const float* m1 = (const float*)d_in[22];
  const float* v1 = (const float*)d_in[23];
  const float* a1 = (const float*)d_in[24];
  const float* W2 = (const float*)d_in[25];
  const float* b2 = (const float*)d_in[26];
  const float* ln0g = (const float*)d_in[27];
  const float* ln0b = (const float*)d_in[28];
  const float* ln1g = (const float*)d_in[29];
  const float* ln1b = (const float*)d_in[30];

  typedef __hip_bfloat16 bf;
  const size_t MB = 1u << 20;
  const size_t KB = 1u << 10;
  char* ws = (char*)d_ws;
  // -------- attention layout (peak 120 MiB) --------
  bf* PR = (bf*)(ws);                      // [8192][4096]  0..64M   P, then R in place
  bf* wot = (bf*)(ws + 64 * MB);           // [512][4096]   64..68M  (pre-loop only)
  bf* wqbf = (bf*)(ws + 68 * MB);          // [8][512][512] 68..72M  (pre-P)
  bf* wkbf = (bf*)(ws + 72 * MB);          // 72..76M
  bf* wvbf = (bf*)(ws + 76 * MB);          // 76..80M (pre-loop)
  bf* wqkt = (bf*)(ws + 80 * MB);          // 80..84M (P only)
  bf* sc = (bf*)(ws + 64 * MB);            // [16][1024][1024] 64..96M (loop)
  bf* kbf = (bf*)(ws + 96 * MB);           // [8192][512]   96..104M
  bf* vbft = (bf*)(ws + 104 * MB);         // [8][512][1024] 104..112M
  bf* qbf = (bf*)(ws + 112 * MB);          // [8192][512]   112..120M (dead after P)
  bf* wvot = (bf*)(ws + 112 * MB);         // [512][4096]   112..116M (after P)
  float* u = (float*)(ws + 116 * MB);                 // [8][8192] 256K
  float* w = (float*)(ws + 116 * MB + 256 * KB);      // 256K
  float* rsum = (float*)(ws + 116 * MB + 512 * KB);   // [64][1024] 256K
  float* t1 = (float*)(ws + 116 * MB + 768 * KB);     // [8][512]
  float* t2 = (float*)(ws + 116 * MB + 784 * KB);
  float* cv = (float*)(ws + 116 * MB + 800 * KB);     // [8]
  float* bvo = (float*)(ws + 116 * MB + 804 * KB);    // [512]
  // -------- post-attention (dead-region reuse, stream-order audited) --------
  float* mhap = (float*)(ws + 64 * MB);    // 2x[8192][512] f32 partials 64..96M (over sc)
  float* xbuf = (float*)(ws);              // [8192][512] f32  0..16M (over R, dead after mha)
  bf* xb = (bf*)(ws + 16 * MB);            // [8192][512] bf16 16..24M
  bf* h0 = (bf*)(ws + 24 * MB);            // [8192][2048] 24..56M
  bf* h1 = (bf*)(ws + 56 * MB);            // [8192][2048] 56..88M (over mhap, dead after LN0)
  float* ffp = (float*)(ws + 24 * MB);     // 2x[8192][512] f32 partials 24..56M (over h0, dead after FF2)
  bf* w0t = (bf*)(ws + 96 * MB);           // [2048][512]  96..98M  (over kbf, dead)
  bf* w1t = (bf*)(ws + 98 * MB);           // [2048][2048] 98..106M
  bf* w2t = (bf*)(ws + 106 * MB);          // [512][2048]  106..108M

  const size_t SD = (size_t)Sd * Dd;       // 524288
  const size_t DD = (size_t)Dd * Dd;       // 262144
  const size_t SS = (size_t)Sd * Sd;       // 1048576
  const size_t SDH = (size_t)Sd * Hd * Dd; // 4194304
  const float* np = nullptr;

  // ---- conversions ----
  conv3<<<dim3(2048, 2), 256, 0, stream>>>(Q, K, K, qbf, kbf, kbf);
  conv3<<<dim3(1024, 3), 256, 0, stream>>>(WQ, WK, WV, wqbf, wkbf, wvbf);
  tconv<<<dim3(8, 16, 8), 256, 0, stream>>>(V, vbft, Dd, Sd, SD, SD);
  tconv<<<dim3(8, 64, 1), 256, 0, stream>>>(Wo, wot, Dd, Hd * Dd, 0, 0);

  // ---- wqkt fold + P (while qbf alive) ----
  bt_gemm<EPI_BF16><<<dim3(4, 4, 8), 256, 0, stream>>>(
      wkbf, Dd, 0, DD, wqbf, Dd, 0, DD, np, 0, 0,
      wqkt, Dd, 0, DD, Dd, 1.f, 3, np, np, np, np, np);
  big_gemm<EPI_BF16><<<dim3(16, 32, 1), 512, 0, stream>>>(
      qbf, Dd, 0, 0, wqkt, 0, np, PR, Hd * Dd, 0, Dd, 1.f, np, np, np, np, np);

  // ---- remaining precompute (qbf region now dead) ----
  bt_gemm<EPI_BF16><<<dim3(4, 4, 8), 256, 0, stream>>>(
      wot, Hd * Dd, 0, 512, wvbf, Dd, 0, DD, np, 0, 0,
      wvot, Hd * Dd, 0, 512, Dd, 1.f, 3, np, np, np, np, np);
  tvec<<<dim3(1024, 2), 256, 0, stream>>>(WQ, bK, WK, bQ, t1, t2);
  uw_kernel<<<Bd * Sd, 256, 0, stream>>>(Q, K, t1, t2, u, w);
  cvec<<<8, 256, 0, stream>>>(bQ, bK, cv);
  bvo_kernel<<<128, 256, 0, stream>>>(wot, bV, bo, bvo);
  hipMemsetAsync(rsum, 0, 64 * 1024 * sizeof(float), stream);

  // ---- attention middle: 2 batches/iter; z-slice->XCD affinity ----
  for (int bp = 0; bp < 4; ++bp) {
    const bf* Ap = PR + (size_t)bp * 2 * SDH;
    big_gemm<EPI_SCORES><<<dim3(4, 4, 16), 512, 0, stream>>>(
        Ap, Hd * Dd, SDH, 512, kbf + (size_t)bp * 2 * SD, SD, np,
        sc, Sd, SS, Dd, 1.f / (float)Dd,
        u + bp * 2048, w + bp * 2048, cv, rsum + bp * 16384, np);
    bt_gemm<EPI_PV, 1><<<dim3(4, 8, 16), 256, 0, stream>>>(
        sc, Sd, 8 * SS, SS, vbft + (size_t)bp * 2 * SD, Sd, SD, 0, np, 0, 0,
        (void*)Ap, Hd * Dd, SDH, 512, Sd, 1.f, 3,
        np, np, np, rsum + bp * 16384, np);
  }

  // ---- mha partials: split-K (z=half), p_z = Rcat[:,zK/2:] @ Wvo[:,zK/2:]^T ----
  bt_gemm<EPI_F32><<<dim3(4, 64, 2), 256, 0, stream>>>(
      PR, Hd * Dd, 2048, 0, wvot, Hd * Dd, 2048, 0, np, 0, 0,
      mhap, Dd, SDH, 0, 2048, 1.f, 0, np, np, np, np, np);
  // x = LN(Q + p0 + p1 + bvo)
  add_ln3<<<Bd * Sd, 256, 0, stream>>>(Q, mhap, mhap + SDH, bvo, ln0g, ln0b, xbuf, xb);

  // ---- FF ----
  tconv<<<dim3(32, 8, 1), 256, 0, stream>>>(W0, w0t, Fd, Dd, 0, 0);
  tconv<<<dim3(32, 32, 1), 256, 0, stream>>>(W1, w1t, Fd, Fd, 0, 0);
  tconv<<<dim3(8, 32, 1), 256, 0, stream>>>(W2, w2t, Dd, Fd, 0, 0);

  big_gemm<EPI_BNPRELU><<<dim3(8, 32, 1), 512, 0, stream>>>(
      xb, Dd, 0, 0, w0t, 0, b0, h0, Fd, 0, Dd, 1.f, g0, be0, m0, v0, a0);
  big_gemm<EPI_BNPRELU><<<dim3(8, 32, 1), 512, 0, stream>>>(
      h0, Fd, 0, 0, w1t, 0, b1, h1, Fd, 0, Fd, 1.f, g1, be1, m1, v1, a1);
  // ff partials: split-K (z=half) of h1 @ w2t^T
  bt_gemm<EPI_F32><<<dim3(4, 64, 2), 256, 0, stream>>>(
      h1, Fd, 1024, 0, w2t, Fd, 1024, 0, np, 0, 0,
      ffp, Dd, SDH, 0, 1024, 1.f, 0, np, np, np, np, np);
  // out = LN(x + f0 + f1 + b2)
  add_ln3<<<Bd * Sd, 256, 0, stream>>>(xbuf, ffp, ffp + SDH, b2, ln1g, ln1b, (float*)d_out, nullptr);
}

// Round 16
// 644.739 us; speedup vs baseline: 1.7261x; 1.0266x over previous
//
#include <hip/hip_runtime.h>
#include <hip/hip_bf16.h>
#include <cstdint>
#include <cstddef>

#define Sd 1024
#define Dd 512
#define Hd 8
#define Fd 2048
#define Bd 8
#define EPSf 1e-3f

typedef __bf16 bf16x8 __attribute__((ext_vector_type(8)));
typedef float f32x4 __attribute__((ext_vector_type(4)));
typedef __attribute__((address_space(3))) unsigned int lds_u32;
typedef __attribute__((address_space(1))) const unsigned int gl_u32;

#define BM 128
#define BN 128
#define BK 32

enum { EPI_BF16 = 0, EPI_F32 = 1, EPI_BNPRELU = 2, EPI_SCORES = 3, EPI_PV = 4 };

__device__ __forceinline__ void gl_lds16(const void* g, void* l) {
  __builtin_amdgcn_global_load_lds((gl_u32*)g, (lds_u32*)l, 16, 0, 0);
}
__device__ inline float b2f(unsigned short u) {
  unsigned x = ((unsigned)u) << 16; float f; __builtin_memcpy(&f, &x, 4); return f;
}
__device__ inline unsigned short f2b(float f) {
  __hip_bfloat16 h = __float2bfloat16(f); unsigned short s; __builtin_memcpy(&s, &h, 2); return s;
}

// ======================================================================
// 256x256 GEMM (frozen R6 core): counted-lgkmcnt pipeline.
// C[M,N] = epi(alpha * A @ Bt^T + bias).
// EPI_SCORES: z-slice pinning via id&7; epilogue stages row sums in LDS
// (barrier-protected), then 256 coalesced global atomics per block.
// ======================================================================

#define LGKM(n)                                                  \
  asm volatile("s_waitcnt lgkmcnt(" #n ")" ::: "memory");        \
  __builtin_amdgcn_sched_barrier(0)
#define VMC(n) asm volatile("s_waitcnt vmcnt(" #n ")" ::: "memory")

#define LDA_(dst, dof, xr, mh)                                               \
  _Pragma("unroll") for (int i_ = 0; i_ < 4; ++i_)                           \
      dst[i_] = *(const bf16x8*)(aw + (dof) + (xr) + (mh) * 8192 + i_ * 2048);
#define LDB_(dst, dof, xr)                                                   \
  _Pragma("unroll") for (int i_ = 0; i_ < 4; ++i_)                           \
      dst[i_] = *(const bf16x8*)(bw + (dof) + (xr) + i_ * 2048);
#define MFMAQ(q, av, bv)                                                     \
  __builtin_amdgcn_s_setprio(1);                                             \
  {                                                                          \
    _Pragma("unroll") for (int i_ = 0; i_ < 4; ++i_) {                       \
      _Pragma("unroll") for (int n_ = 0; n_ < 4; ++n_)                       \
          acc[(q) * 4 + i_][n_] = __builtin_amdgcn_mfma_f32_16x16x32_bf16(   \
              av[i_], bv[n_], acc[(q) * 4 + i_][n_], 0, 0, 0);               \
    }                                                                        \
  }                                                                          \
  __builtin_amdgcn_s_setprio(0)

template <int EPI>
__global__ __launch_bounds__(512, 2) void big_gemm(
    const __hip_bfloat16* __restrict__ A_, int lda, size_t sA1, size_t sA2,
    const __hip_bfloat16* __restrict__ B_, size_t sB1,
    const float* __restrict__ bias_,
    void* __restrict__ C_, int ldc, size_t sC, int K, float alpha,
    const float* __restrict__ bn_g, const float* __restrict__ bn_b,
    const float* __restrict__ bn_m, const float* __restrict__ bn_v,
    const float* __restrict__ pa) {
  __shared__ __align__(16) char lds[131072];
  const int tid = threadIdx.x;
  const int gx = gridDim.x;
  int bx, by, z;
  if (EPI == EPI_SCORES) {
    const int id = blockIdx.x + gx * (blockIdx.y + gridDim.y * blockIdx.z);
    const int bps = gx * gridDim.y;
    const int xcd = id & 7, slot = id >> 3;
    const int sl = slot / bps, inner = slot % bps;
    z = xcd + 8 * sl;
    bx = inner % gx;
    by = inner / gx;
  } else {
    const int nwg = gx * gridDim.y;
    const int orig = blockIdx.y * gx + blockIdx.x;
    const int wgid = (orig & 7) * (nwg >> 3) + (orig >> 3);
    bx = wgid % gx;
    by = wgid / gx;
    z = blockIdx.z;
  }
  const int m0 = by * 256, n0 = bx * 256;
  const int z1 = z >> 3, z2 = z & 7;

  const int lane = tid & 63;
  const int wid = tid >> 6;
  const int wm = wid >> 2;
  const int wn = wid & 3;
  const int fr = lane & 15;
  const int kg = lane >> 4;

  const int r0 = tid >> 3;
  const int c0 = (tid & 7) ^ (r0 & 7);
  const size_t lda2 = (size_t)lda * 2;
  const size_t ldb2 = (size_t)K * 2;
  const char* Ab = (const char*)(A_ + (size_t)z1 * sA1 + (size_t)z2 * sA2) +
                   (size_t)(m0 + r0) * lda2 + c0 * 16;
  const char* Bb = (const char*)(B_ + (size_t)z1 * sB1) + (size_t)(n0 + r0) * ldb2 + c0 * 16;

  const int axor0 = (kg ^ (fr & 7)) << 4;
  const int axor1 = ((4 + kg) ^ (fr & 7)) << 4;
  const char* aw = lds + (wm << 14) + fr * 128;
  const char* bw = lds + 32768 + ((wn >> 1) << 14) + ((wn & 1) << 13) + fr * 128;

  auto STG = [&](int nof, int H, int u) {  // H: 0=A0 1=A1 2=B0 3=B1
    char* L = lds + nof + (H << 14) + tid * 16;
    const size_t rs = (H < 2) ? lda2 : ldb2;
    const char* src = ((H < 2) ? Ab : Bb) + (size_t)((H & 1) * 128) * rs + (size_t)u * 128;
    gl_lds16(src, L);
    gl_lds16(src + 64 * rs, L + 8192);
  };

  bf16x8 aA[4], aB[4], bA[4], bB[4];
  f32x4 acc[8][4] = {};
  const int NT = K >> 6;

  STG(0, 0, 0); STG(0, 1, 0); STG(0, 2, 0); STG(0, 3, 0);
  STG(65536, 0, 1); STG(65536, 1, 1); STG(65536, 2, 1); STG(65536, 3, 1);
  VMC(8);
  __builtin_amdgcn_s_barrier();
  LDA_(aA, 0, axor0, 0);
  LDB_(bA, 0, axor0);

  for (int u = 0; u < NT; ++u) {
    const int dof = (u & 1) << 16;
    const int nof = dof ^ 65536;
    const bool stg = (u >= 1) & (u + 1 < NT);
    LDA_(aB, dof, axor0, 1);
    if (stg) { STG(nof, 0, u + 1); STG(nof, 1, u + 1); }
    LGKM(4);
    MFMAQ(0, aA, bA);
    LDA_(aA, dof, axor1, 0);
    LDB_(bB, dof, axor1);
    if (stg) { STG(nof, 2, u + 1); STG(nof, 3, u + 1); }
    LGKM(8);
    MFMAQ(1, aB, bA);
    LDA_(aB, dof, axor1, 1);
    LGKM(4);
    MFMAQ(0, aA, bB);
    LGKM(0);
    if (u + 1 < NT) {
      VMC(0);
      __builtin_amdgcn_s_barrier();
      LDA_(aA, nof, axor0, 0);
      LDB_(bA, nof, axor0);
    }
    MFMAQ(1, aB, bB);
  }

  // epilogue: C/D layout col=lane&15, row=(lane>>4)*4+j [m89-verified]
  char* C = (char*)C_ + (size_t)z * sC * ((EPI == EPI_F32) ? 4 : 2);
  if (EPI == EPI_SCORES) {
    const float cvv = bn_m[z2];
    const float* ub = bn_g + (size_t)z2 * 8192 + (size_t)z1 * 1024;
    const float* wb = bn_b + (size_t)z2 * 8192 + (size_t)z1 * 1024;
    float* rs = (float*)bn_v + ((size_t)z << 10);
    float* rsl = (float*)lds;  // [256] block-local row sums
    __syncthreads();           // all frag ds_reads done before LDS reuse
    if (tid < 256) rsl[tid] = 0.f;
    __syncthreads();
    float wc[4];
#pragma unroll
    for (int ni = 0; ni < 4; ++ni) wc[ni] = wb[n0 + wn * 64 + ni * 16 + fr];
#pragma unroll
    for (int mi = 0; mi < 8; ++mi) {
      const int rb = m0 + wm * 128 + mi * 16 + kg * 4;
      float rowa[4] = {0.f, 0.f, 0.f, 0.f};
#pragma unroll
      for (int ni = 0; ni < 4; ++ni) {
        const int col = n0 + wn * 64 + ni * 16 + fr;
#pragma unroll
        for (int j = 0; j < 4; ++j) {
          const int row = rb + j;
          const float e = __expf((acc[mi][ni][j] + ub[row] + wc[ni] + cvv) * alpha);
          rowa[j] += e;
          ((__hip_bfloat16*)C)[(size_t)row * ldc + col] = __float2bfloat16(e);
        }
      }
#pragma unroll
      for (int j = 0; j < 4; ++j) {
        float v = rowa[j];
        v += __shfl_xor(v, 1);
        v += __shfl_xor(v, 2);
        v += __shfl_xor(v, 4);
        v += __shfl_xor(v, 8);
        if (fr == 0) atomicAdd(&rsl[wm * 128 + mi * 16 + kg * 4 + j], v);
      }
    }
    __syncthreads();
    if (tid < 256) atomicAdd(rs + m0 + tid, rsl[tid]);
  } else {
#pragma unroll
    for (int ni = 0; ni < 4; ++ni) {
      const int col = n0 + wn * 64 + ni * 16 + fr;
      float bcol = 0.f, scale = 0.f, shift = 0.f;
      if (EPI != EPI_BF16) bcol = bias_[col];
      if (EPI == EPI_BNPRELU) {
        scale = bn_g[col] * rsqrtf(bn_v[col] + EPSf);
        shift = bn_b[col] - bn_m[col] * scale;
      }
#pragma unroll
      for (int mi = 0; mi < 8; ++mi) {
        const int rb = m0 + wm * 128 + mi * 16 + kg * 4;
#pragma unroll
        for (int j = 0; j < 4; ++j) {
          const int row = rb + j;
          float v = acc[mi][ni][j] * alpha + bcol;
          if (EPI == EPI_F32) {
            ((float*)C)[(size_t)row * ldc + col] = v;
          } else if (EPI == EPI_BF16) {
            ((__hip_bfloat16*)C)[(size_t)row * ldc + col] = __float2bfloat16(v);
          } else {
            v = v * scale + shift;
            const float aa = pa[(size_t)(row & (Sd - 1)) * Fd + col];
            v = v > 0.f ? v : aa * v;
            ((__hip_bfloat16*)C)[(size_t)row * ldc + col] = __float2bfloat16(v);
          }
        }
      }
    }
  }
}

// ---- m97-structure BT-GEMM (PV/mha/FF3/folding) ----
template <int EPI, int XCDZ = 0>
__global__ __launch_bounds__(256, 2) void bt_gemm(
    const __hip_bfloat16* __restrict__ A_, int lda, size_t sA1, size_t sA2,
    const __hip_bfloat16* __restrict__ B_, int ldb, size_t sB1, size_t sB2,
    const float* __restrict__ bias_, size_t sBi1, size_t sBi2,
    void* __restrict__ C_, int ldc, size_t sC1, size_t sC2,
    int K, float alpha, int zshift,
    const float* __restrict__ bn_g, const float* __restrict__ bn_b,
    const float* __restrict__ bn_m, const float* __restrict__ bn_v,
    const float* __restrict__ pa) {
  __shared__ __hip_bfloat16 As[BM * BK];
  __shared__ __hip_bfloat16 Bs[BN * BK];

  const int tid = threadIdx.x;
  int bxq, byq, z;
  if (XCDZ) {
    const int gx = gridDim.x;
    const int id = blockIdx.x + gx * (blockIdx.y + gridDim.y * blockIdx.z);
    const int bps = gx * gridDim.y;
    const int xcd = id & 7, slot = id >> 3;
    const int sl = slot / bps, inner = slot % bps;
    z = xcd + 8 * sl;
    bxq = inner % gx;
    byq = inner / gx;
  } else {
    bxq = blockIdx.x;
    byq = blockIdx.y;
    z = blockIdx.z;
  }
  const int z1 = z >> zshift;
  const int z2 = z & ((1 << zshift) - 1);
  const int m0 = byq * BM;
  const int n0 = bxq * BN;

  const __hip_bfloat16* A = A_ + (size_t)z1 * sA1 + (size_t)z2 * sA2;
  const __hip_bfloat16* Bt = B_ + (size_t)z1 * sB1 + (size_t)z2 * sB2;
  const float* bi = bias_ ? bias_ + (size_t)z1 * sBi1 + (size_t)z2 * sBi2 : nullptr;

  const int lane = tid & 63;
  const int wv = tid >> 6;
  const int wm = (wv >> 1) * 64;
  const int wn = (wv & 1) * 64;
  const int fr = lane & 15;
  const int kg = lane >> 4;

  const int srow = tid >> 2, sch = tid & 3;
  const size_t ldab = (size_t)lda * 2, ldbb = (size_t)ldb * 2;
  const char* Ap = (const char*)A + (size_t)(m0 + srow) * ldab + sch * 16;
  const char* Ap2 = Ap + 64 * ldab;
  const char* Bp = (const char*)Bt + (size_t)(n0 + srow) * ldbb + sch * 16;
  const char* Bp2 = Bp + 64 * ldbb;
  char* lA = (char*)As + tid * 16;
  char* lB = (char*)Bs + tid * 16;

  f32x4 acc[4][4] = {};

  for (int kt = 0; kt < K; kt += BK) {
    const size_t kb = (size_t)kt * 2;
    gl_lds16(Ap + kb, lA);
    gl_lds16(Ap2 + kb, lA + 4096);
    gl_lds16(Bp + kb, lB);
    gl_lds16(Bp2 + kb, lB + 4096);
    __syncthreads();

    bf16x8 afr[4], bfr[4];
#pragma unroll
    for (int mi = 0; mi < 4; ++mi)
      afr[mi] = *reinterpret_cast<const bf16x8*>(As + (wm + mi * 16 + fr) * BK + kg * 8);
#pragma unroll
    for (int ni = 0; ni < 4; ++ni)
      bfr[ni] = *reinterpret_cast<const bf16x8*>(Bs + (wn + ni * 16 + fr) * BK + kg * 8);
#pragma unroll
    for (int mi = 0; mi < 4; ++mi)
#pragma unroll
      for (int ni = 0; ni < 4; ++ni)
        acc[mi][ni] = __builtin_amdgcn_mfma_f32_16x16x32_bf16(afr[mi], bfr[ni], acc[mi][ni], 0, 0, 0);
    __syncthreads();
  }

  char* C = (char*)C_ + ((size_t)z1 * sC1 + (size_t)z2 * sC2) * ((EPI == EPI_F32) ? 4 : 2);
  float rinv_[4][4];
  if (EPI == EPI_PV) {
#pragma unroll
    for (int mi = 0; mi < 4; ++mi)
#pragma unroll
      for (int j = 0; j < 4; ++j)
        rinv_[mi][j] = 1.0f / bn_v[((size_t)z << 10) + m0 + wm + mi * 16 + kg * 4 + j];
  }
#pragma unroll
  for (int ni = 0; ni < 4; ++ni) {
    const int col = n0 + wn + ni * 16 + fr;
    float bcol = 0.f, scale = 0.f, shift = 0.f;
    if (bi) bcol = bi[col];
    if (EPI == EPI_BNPRELU) {
      scale = bn_g[col] * rsqrtf(bn_v[col] + EPSf);
      shift = bn_b[col] - bn_m[col] * scale;
    }
#pragma unroll
    for (int mi = 0; mi < 4; ++mi) {
      const int rb = m0 + wm + mi * 16 + kg * 4;
#pragma unroll
      for (int j = 0; j < 4; ++j) {
        const int row = rb + j;
        if (EPI == EPI_PV) {
          ((__hip_bfloat16*)C)[(size_t)row * ldc + col] = __float2bfloat16(acc[mi][ni][j] * rinv_[mi][j]);
        } else {
          float v = acc[mi][ni][j] * alpha + bcol;
          if (EPI == EPI_F32) {
            ((float*)C)[(size_t)row * ldc + col] = v;
          } else if (EPI == EPI_BF16) {
            ((__hip_bfloat16*)C)[(size_t)row * ldc + col] = __float2bfloat16(v);
          } else {
            v = v * scale + shift;
            const float a = pa[(size_t)(row & (Sd - 1)) * Fd + col];
            v = v > 0.f ? v : a * v;
            ((__hip_bfloat16*)C)[(size_t)row * ldc + col] = __float2bfloat16(v);
          }
        }
      }
    }
  }
}

// ---- transpose + convert: src [K][N] f32 -> dst [N][Kfull] bf16 ----
__global__ __launch_bounds__(256) void tconv(const float* __restrict__ src,
                                             __hip_bfloat16* __restrict__ dst,
                                             int N, int Kfull, size_t sIn, size_t sOut) {
  __shared__ __hip_bfloat16 t[64][65];
  const float* s = src + (size_t)blockIdx.z * sIn;
  __hip_bfloat16* d = dst + (size_t)blockIdx.z * sOut;
  const int k0 = blockIdx.y * 64, n0 = blockIdx.x * 64;
  const int tid = threadIdx.x;
#pragma unroll
  for (int i = 0; i < 4; ++i) {
    int slot = tid + i * 256;
    int r = slot >> 4, c = (slot & 15) * 4;
    const float4 v = *reinterpret_cast<const float4*>(s + (size_t)(k0 + r) * N + n0 + c);
    t[c + 0][r] = __float2bfloat16(v.x);
    t[c + 1][r] = __float2bfloat16(v.y);
    t[c + 2][r] = __float2bfloat16(v.z);
    t[c + 3][r] = __float2bfloat16(v.w);
  }
  __syncthreads();
#pragma unroll
  for (int i = 0; i < 2; ++i) {
    int slot = tid + i * 256;
    int n = slot >> 3, kc = (slot & 7) * 8;
    __hip_bfloat16 tmp[8];
#pragma unroll
    for (int j = 0; j < 8; ++j) tmp[j] = t[n][kc + j];
    *reinterpret_cast<float4*>(d + (size_t)(n0 + n) * Kfull + k0 + kc) =
        *reinterpret_cast<const float4*>(tmp);
  }
}

// ---- f32 -> bf16 elementwise; grid (nblk, ntensors), 8 elems/thread ----
__global__ __launch_bounds__(256) void conv3(const float* __restrict__ s0, const float* __restrict__ s1,
                                             const float* __restrict__ s2,
                                             __hip_bfloat16* __restrict__ d0, __hip_bfloat16* __restrict__ d1,
                                             __hip_bfloat16* __restrict__ d2) {
  const float* s = blockIdx.y == 0 ? s0 : (blockIdx.y == 1 ? s1 : s2);
  __hip_bfloat16* d = blockIdx.y == 0 ? d0 : (blockIdx.y == 1 ? d1 : d2);
  const size_t i = (size_t)blockIdx.x * 256 + threadIdx.x;
  const float4 a = reinterpret_cast<const float4*>(s)[2 * i];
  const float4 b = reinterpret_cast<const float4*>(s)[2 * i + 1];
  __hip_bfloat16 tmp[8] = {
      __float2bfloat16(a.x), __float2bfloat16(a.y), __float2bfloat16(a.z), __float2bfloat16(a.w),
      __float2bfloat16(b.x), __float2bfloat16(b.y), __float2bfloat16(b.z), __float2bfloat16(b.w)};
  *reinterpret_cast<float4*>(d + 8 * i) = *reinterpret_cast<const float4*>(tmp);
}

// ---- reductions ----
__device__ inline float wave_sum(float v) {
#pragma unroll
  for (int o = 32; o > 0; o >>= 1) v += __shfl_xor(v, o);
  return v;
}

// t1[hd] = sum_e WQ[h][d][e]*bK[h][e] (y=0); t2[hd] = sum_e WK[h][d][e]*bQ[h][e] (y=1)
__global__ __launch_bounds__(256) void tvec(const float* __restrict__ WQ, const float* __restrict__ bK,
                                            const float* __restrict__ WK, const float* __restrict__ bQ,
                                            float* __restrict__ t1, float* __restrict__ t2) {
  const float* W = blockIdx.y == 0 ? WQ : WK;
  const float* bb = blockIdx.y == 0 ? bK : bQ;
  float* out = blockIdx.y == 0 ? t1 : t2;
  const int wv = threadIdx.x >> 6, lane = threadIdx.x & 63;
  const int hd = blockIdx.x * 4 + wv;
  const int h = hd >> 9;
  float acc = 0.f;
#pragma unroll
  for (int j = 0; j < 8; ++j) {
    const int e = lane + 64 * j;
    acc += W[(size_t)hd * 512 + e] * bb[h * 512 + e];
  }
  acc = wave_sum(acc);
  if (lane == 0) out[hd] = acc;
}

// Merged Q/K prep: u[h][row] = Q[row]·t1[h], w[h][row] = K[row]·t2[h],
// plus bf16 conversion of Q,K rows. grid (8192), 256 thr.
__global__ __launch_bounds__(256) void qk_prep(const float* __restrict__ Q, const float* __restrict__ K,
                                               const float* __restrict__ t1, const float* __restrict__ t2,
                                               float* __restrict__ u, float* __restrict__ w,
                                               __hip_bfloat16* __restrict__ qbf,
                                               __hip_bfloat16* __restrict__ kbf) {
  const int tid = threadIdx.x;
  const size_t row = blockIdx.x;
  const float2 q = reinterpret_cast<const float2*>(Q + row * 512)[tid];
  const float2 k = reinterpret_cast<const float2*>(K + row * 512)[tid];
  ((unsigned int*)qbf)[row * 256 + tid] = (unsigned)f2b(q.x) | ((unsigned)f2b(q.y) << 16);
  ((unsigned int*)kbf)[row * 256 + tid] = (unsigned)f2b(k.x) | ((unsigned)f2b(k.y) << 16);
  const int c = tid * 2;
  __shared__ float redu[8][4], redw[8][4];
  const int wv = tid >> 6;
#pragma unroll
  for (int h = 0; h < 8; ++h) {
    float ua = q.x * t1[h * 512 + c] + q.y * t1[h * 512 + c + 1];
    float wa = k.x * t2[h * 512 + c] + k.y * t2[h * 512 + c + 1];
    ua = wave_sum(ua);
    wa = wave_sum(wa);
    if ((tid & 63) == 0) { redu[h][wv] = ua; redw[h][wv] = wa; }
  }
  __syncthreads();
  if (tid < 8)
    u[tid * 8192 + row] = redu[tid][0] + redu[tid][1] + redu[tid][2] + redu[tid][3];
  else if (tid < 16)
    w[(tid - 8) * 8192 + row] = redw[tid - 8][0] + redw[tid - 8][1] + redw[tid - 8][2] + redw[tid - 8][3];
}

// c[h] = bQ[h]·bK[h]. grid (8), 256 thr.
__global__ __launch_bounds__(256) void cvec(const float* __restrict__ bQ, const float* __restrict__ bK,
                                            float* __restrict__ c) {
  const int h = blockIdx.x, tid = threadIdx.x;
  const float2 a = reinterpret_cast<const float2*>(bQ + h * 512)[tid];
  const float2 b = reinterpret_cast<const float2*>(bK + h * 512)[tid];
  float acc = wave_sum(a.x * b.x + a.y * b.y);
  __shared__ float red[4];
  if ((tid & 63) == 0) red[tid >> 6] = acc;
  __syncthreads();
  if (tid == 0) c[h] = red[0] + red[1] + red[2] + red[3];
}

// bvo[e] = bo[e] + sum_hd wot[e][hd]*bV[hd]. grid (128), 256 thr.
__global__ __launch_bounds__(256) void bvo_kernel(const __hip_bfloat16* __restrict__ wot,
                                                  const float* __restrict__ bV,
                                                  const float* __restrict__ bo,
                                                  float* __restrict__ bvo) {
  const int wv = threadIdx.x >> 6, lane = threadIdx.x & 63;
  const int e = blockIdx.x * 4 + wv;
  float acc = 0.f;
#pragma unroll
  for (int j = 0; j < 64; ++j) {
    const int hd = lane + 64 * j;
    acc += b2f(*(const unsigned short*)&wot[(size_t)e * 4096 + hd]) * bV[hd];
  }
  acc = wave_sum(acc);
  if (lane == 0) bvo[e] = bo[e] + acc;
}

// out = LN(Xa + Xb + Xc + cb[col])*gamma + beta (rows of 512). grid(8192), 256 thr.
__global__ __launch_bounds__(256) void add_ln3(const float* __restrict__ Xa, const float* __restrict__ Xb,
                                               const float* __restrict__ Xc, const float* __restrict__ cb,
                                               const float* __restrict__ gamma, const float* __restrict__ beta,
                                               float* __restrict__ out, __hip_bfloat16* __restrict__ outb) {
  const int tid = threadIdx.x;
  const size_t base = (size_t)blockIdx.x * Dd;
  const float2 a = reinterpret_cast<const float2*>(Xa + base)[tid];
  const float2 b = reinterpret_cast<const float2*>(Xb + base)[tid];
  const float2 c2 = reinterpret_cast<const float2*>(Xc + base)[tid];
  const int c = tid * 2;
  const float r0 = a.x + b.x + c2.x + cb[c];
  const float r1 = a.y + b.y + c2.y + cb[c + 1];
  float s = wave_sum(r0 + r1);
  float q = wave_sum(r0 * r0 + r1 * r1);
  __shared__ float rs[4], rq[4];
  if ((tid & 63) == 0) { rs[tid >> 6] = s; rq[tid >> 6] = q; }
  __syncthreads();
  const float mean = (rs[0] + rs[1] + rs[2] + rs[3]) * (1.f / Dd);
  const float msq = (rq[0] + rq[1] + rq[2] + rq[3]) * (1.f / Dd);
  const float inv = rsqrtf(msq - mean * mean + EPSf);
  const float y0 = (r0 - mean) * inv * gamma[c] + beta[c];
  const float y1 = (r1 - mean) * inv * gamma[c + 1] + beta[c + 1];
  out[base + c] = y0;
  out[base + c + 1] = y1;
  if (outb) {
    outb[base + c] = __float2bfloat16(y0);
    outb[base + c + 1] = __float2bfloat16(y1);
  }
}

extern "C" void kernel_launch(void* const* d_in, const int* in_sizes, int n_in,
                              void* d_out, int out_size, void* d_ws, size_t ws_size,
                              hipStream_t stream) {
  const float* Q = (const float*)d_in[0];
  const float* K = (const float*)d_in[1];
  const float* V = (const float*)d_in[2];
  const float* WQ = (const float*)d_in[3];
  const float* bQ = (const float*)d_in[4];
  const float* WK = (const float*)d_in[5];
  const float* bK = (const float*)d_in[6];
  const float* WV = (const float*)d_in[7];
  const float* bV = (const float*)d_in[8];
  const float* Wo = (const float*)d_in[9];
  const float* bo = (const float*)d_in[10];
  const float* W0 = (const float*)d_in[11];
  const float* b0 = (const float*)d_in[12];
  const float* g0 = (const float*)d_in[13];
  const float* be0 = (const float*)d_in[14];
  const float* m0 = (const float*)d_in[15];
  const float* v0 = (const float*)d_in[16];
  const float* a0 = (const float*)d_in[17];
  const float* W1 = (const float*)d_in[18];
  const float* b1 = (const float*)d_in[19];
  const float* g1 = (const float*)d_in[20];
  const float* be1 = (const float*)d_in[21];
  const float* m1 = (const float*)d_in[22];
  const float* v1 = (const float*)d_in[23];
  const float* a1 = (const float*)d_in[24];
  const float* W2 = (const float*)d_in[25];
  const float* b2 = (const float*)d_in[26];
  const float* ln0g = (const float*)d_in[27];
  const float* ln0b = (const float*)d_in[28];
  const float* ln1g = (const float*)d_in[29];
  const float* ln1b = (const float*)d_in[30];

  typedef __hip_bfloat16 bf;
  const size_t MB = 1u << 20;
  const size_t KB = 1u << 10;
  char* ws = (char*)d_ws;
  // -------- attention layout (peak 120 MiB) --------
  // qbf moved to 84..92M (free between wqkt-end and sc slices 10..13,
  // which are only written AFTER P consumed qbf). u/w/... at 116M+ no
  // longer collide with any live buffer (R15 bug fix).
  bf* PR = (bf*)(ws);                      // [8192][4096]  0..64M   P, then R in place
  bf* wot = (bf*)(ws + 64 * MB);           // [512][4096]   64..68M  (pre-loop only)
  bf* wqbf = (bf*)(ws + 68 * MB);          // [8][512][512] 68..72M  (pre-P)
  bf* wkbf = (bf*)(ws + 72 * MB);          // 72..76M
  bf* wvbf = (bf*)(ws + 76 * MB);          // 76..80M (pre-loop)
  bf* wqkt = (bf*)(ws + 80 * MB);          // 80..84M (P only)
  bf* qbf = (bf*)(ws + 84 * MB);           // [8192][512]   84..92M (dead after P)
  bf* sc = (bf*)(ws + 64 * MB);            // [16][1024][1024] 64..96M (loop; after P)
  bf* kbf = (bf*)(ws + 96 * MB);           // [8192][512]   96..104M
  bf* vbft = (bf*)(ws + 104 * MB);         // [8][512][1024] 104..112M
  bf* wvot = (bf*)(ws + 112 * MB);         // [512][4096]   112..116M (after P)
  float* u = (float*)(ws + 116 * MB);                 // [8][8192] 256K
  float* w = (float*)(ws + 116 * MB + 256 * KB);      // 256K
  float* rsum = (float*)(ws + 116 * MB + 512 * KB);   // [64][1024] 256K
  float* t1 = (float*)(ws + 116 * MB + 768 * KB);     // [8][512]
  float* t2 = (float*)(ws + 116 * MB + 784 * KB);
  float* cv = (float*)(ws + 116 * MB + 800 * KB);     // [8]
  float* bvo = (float*)(ws + 116 * MB + 804 * KB);    // [512]
  // -------- post-attention (dead-region reuse, stream-order audited) --------
  float* mhap = (float*)(ws + 64 * MB);    // 2x[8192][512] f32 partials 64..96M (over sc)
  float* xbuf = (float*)(ws);              // [8192][512] f32  0..16M (over R, dead after mha)
  bf* xb = (bf*)(ws + 16 * MB);            // [8192][512] bf16 16..24M
  bf* h0 = (bf*)(ws + 24 * MB);            // [8192][2048] 24..56M
  bf* h1 = (bf*)(ws + 56 * MB);            // [8192][2048] 56..88M (over mhap, dead after LN0)
  float* ffp = (float*)(ws + 24 * MB);     // 2x[8192][512] f32 partials 24..56M (over h0, dead after FF2)
  bf* w0t = (bf*)(ws + 96 * MB);           // [2048][512]  96..98M  (over kbf, dead)
  bf* w1t = (bf*)(ws + 98 * MB);           // [2048][2048] 98..106M
  bf* w2t = (bf*)(ws + 106 * MB);          // [512][2048]  106..108M

  const size_t SD = (size_t)Sd * Dd;       // 524288
  const size_t DD = (size_t)Dd * Dd;       // 262144
  const size_t SS = (size_t)Sd * Sd;       // 1048576
  const size_t SDH = (size_t)Sd * Hd * Dd; // 4194304
  const float* np = nullptr;

  // ---- precompute ----
  tvec<<<dim3(1024, 2), 256, 0, stream>>>(WQ, bK, WK, bQ, t1, t2);
  qk_prep<<<Bd * Sd, 256, 0, stream>>>(Q, K, t1, t2, u, w, qbf, kbf);
  conv3<<<dim3(1024, 3), 256, 0, stream>>>(WQ, WK, WV, wqbf, wkbf, wvbf);
  tconv<<<dim3(8, 16, 8), 256, 0, stream>>>(V, vbft, Dd, Sd, SD, SD);
  tconv<<<dim3(8, 64, 1), 256, 0, stream>>>(Wo, wot, Dd, Hd * Dd, 0, 0);

  // ---- wqkt fold + P (while qbf alive) ----
  bt_gemm<EPI_BF16><<<dim3(4, 4, 8), 256, 0, stream>>>(
      wkbf, Dd, 0, DD, wqbf, Dd, 0, DD, np, 0, 0,
      wqkt, Dd, 0, DD, Dd, 1.f, 3, np, np, np, np, np);
  big_gemm<EPI_BF16><<<dim3(16, 32, 1), 512, 0, stream>>>(
      qbf, Dd, 0, 0, wqkt, 0, np, PR, Hd * Dd, 0, Dd, 1.f, np, np, np, np, np);

  // ---- remaining precompute (qbf region now dead) ----
  bt_gemm<EPI_BF16><<<dim3(4, 4, 8), 256, 0, stream>>>(
      wot, Hd * Dd, 0, 512, wvbf, Dd, 0, DD, np, 0, 0,
      wvot, Hd * Dd, 0, 512, Dd, 1.f, 3, np, np, np, np, np);
  cvec<<<8, 256, 0, stream>>>(bQ, bK, cv);
  bvo_kernel<<<128, 256, 0, stream>>>(wot, bV, bo, bvo);
  hipMemsetAsync(rsum, 0, 64 * 1024 * sizeof(float), stream);

  // ---- attention middle: 2 batches/iter ----
  for (int bp = 0; bp < 4; ++bp) {
    const bf* Ap = PR + (size_t)bp * 2 * SDH;
    big_gemm<EPI_SCORES><<<dim3(4, 4, 16), 512, 0, stream>>>(
        Ap, Hd * Dd, SDH, 512, kbf + (size_t)bp * 2 * SD, SD, np,
        sc, Sd, SS, Dd, 1.f / (float)Dd,
        u + bp * 2048, w + bp * 2048, cv, rsum + bp * 16384, np);
    bt_gemm<EPI_PV, 1><<<dim3(4, 8, 16), 256, 0, stream>>>(
        sc, Sd, 8 * SS, SS, vbft + (size_t)bp * 2 * SD, Sd, SD, 0, np, 0, 0,
        (void*)Ap, Hd * Dd, SDH, 512, Sd, 1.f, 3,
        np, np, np, rsum + bp * 16384, np);
  }

  // ---- mha partials: split-K (z=half), p_z = Rcat[:,zK/2:] @ Wvo[:,zK/2:]^T ----
  bt_gemm<EPI_F32><<<dim3(4, 64, 2), 256, 0, stream>>>(
      PR, Hd * Dd, 2048, 0, wvot, Hd * Dd, 2048, 0, np, 0, 0,
      mhap, Dd, SDH, 0, 2048, 1.f, 0, np, np, np, np, np);
  // x = LN(Q + p0 + p1 + bvo)
  add_ln3<<<Bd * Sd, 256, 0, stream>>>(Q, mhap, mhap + SDH, bvo, ln0g, ln0b, xbuf, xb);

  // ---- FF ----
  tconv<<<dim3(32, 8, 1), 256, 0, stream>>>(W0, w0t, Fd, Dd, 0, 0);
  tconv<<<dim3(32, 32, 1), 256, 0, stream>>>(W1, w1t, Fd, Fd, 0, 0);
  tconv<<<dim3(8, 32, 1), 256, 0, stream>>>(W2, w2t, Dd, Fd, 0, 0);

  big_gemm<EPI_BNPRELU><<<dim3(8, 32, 1), 512, 0, stream>>>(
      xb, Dd, 0, 0, w0t, 0, b0, h0, Fd, 0, Dd, 1.f, g0, be0, m0, v0, a0);
  big_gemm<EPI_BNPRELU><<<dim3(8, 32, 1), 512, 0, stream>>>(
      h0, Fd, 0, 0, w1t, 0, b1, h1, Fd, 0, Fd, 1.f, g1, be1, m1, v1, a1);
  // ff partials: split-K (z=half) of h1 @ w2t^T
  bt_gemm<EPI_F32><<<dim3(4, 64, 2), 256, 0, stream>>>(
      h1, Fd, 1024, 0, w2t, Fd, 1024, 0, np, 0, 0,
      ffp, Dd, SDH, 0, 1024, 1.f, 0, np, np, np, np, np);
  // out = LN(x + f0 + f1 + b2)
  add_ln3<<<Bd * Sd, 256, 0, stream>>>(xbuf, ffp, ffp + SDH, b2, ln1g, ln1b, (float*)d_out, nullptr);
}